// Round 4
// baseline (559.332 us; speedup 1.0000x reference)
//
#include <hip/hip_runtime.h>
#include <hip/hip_cooperative_groups.h>
#include <stdint.h>

namespace cg = cooperative_groups;

#define K_TOP 1000
#define PST 0.05f
#define THR 256
#define GRID 512            // 2 blocks/CU on 256 CUs, guaranteed by launch_bounds+LDS
#define STRIDE (GRID * THR) // 131072
#define SMAX 2              // anchors per thread (covers A <= 262144)

// ---- ctrl words ----
#define C_CNTA 6
#define C_CNTE 7

__device__ __forceinline__ unsigned mapU(float f) {
  unsigned b = __float_as_uint(f);
  return (b & 0x80000000u) ? ~b : (b | 0x80000000u);
}
__device__ __forceinline__ float unmapU(unsigned u) {
  unsigned b = (u & 0x80000000u) ? (u ^ 0x80000000u) : ~u;
  return __uint_as_float(b);
}

__device__ __forceinline__ float scalar_dim(const int* p) {
  int v = *p;
  if (v > 0 && v < (1 << 20)) return (float)v;
  return __int_as_float(v);
}

// Wave-0 radix bin selection; runs redundantly per block, results in LDS.
__device__ void select_lds(const unsigned* __restrict__ histL, int shift,
                           unsigned* sPref, unsigned* sCum) {
  int t = threadIdx.x;                       // caller guards t < 64
  unsigned cumIn = *sCum;
  unsigned need = (unsigned)K_TOP - cumIn;   // >= 1
  unsigned h0 = histL[4 * t + 0], h1 = histL[4 * t + 1];
  unsigned h2 = histL[4 * t + 2], h3 = histL[4 * t + 3];
  unsigned v = h0 + h1 + h2 + h3;
  #pragma unroll
  for (int d = 1; d < 64; d <<= 1) {         // inclusive suffix-sum
    unsigned q = __shfl_down(v, d);
    if (t + d < 64) v += q;
  }
  unsigned sn = __shfl_down(v, 1);
  if (t == 63) sn = 0;
  if (v >= need && sn < need) {              // exactly one lane wins
    unsigned c = sn;
    unsigned hh[4] = {h0, h1, h2, h3};
    int bsel = 4 * t;
    for (int b = 3; b >= 0; --b) {
      if (c + hh[b] >= need) { bsel = 4 * t + b; break; }
      c += hh[b];
    }
    *sPref = *sPref | (((unsigned)bsel) << shift);
    *sCum = cumIn + c;                       // strictly-above count
  }
}

__global__ void __launch_bounds__(1024) k_init(unsigned* hist, unsigned* ctrl,
                                               unsigned long long* keyBuf,
                                               float* candS, int* candC,
                                               float4* candB) {
  int t = threadIdx.x;
  hist[t] = 0u;                              // 4 levels x 256 bins
  if (t < 64) ctrl[t] = 0u;
  for (int e = t; e < 4096; e += 1024) keyBuf[e] = 0ull;
  candS[t] = -1.0f;
  candC[t] = -1;
  candB[t] = make_float4(0.f, 0.f, 0.f, 0.f);
}

__global__ void __launch_bounds__(THR, 2) k_main(
    const float* __restrict__ cls, const float* __restrict__ reg,
    const float* __restrict__ anc, const int* __restrict__ hp,
    const int* __restrict__ wp, int A, int C,
    float4* __restrict__ boxes, int* __restrict__ ci,
    unsigned long long* __restrict__ keyBuf,
    float* __restrict__ candS, int* __restrict__ candC,
    float4* __restrict__ candB, unsigned long long* __restrict__ maskBuf,
    unsigned* __restrict__ hist, unsigned* __restrict__ ctrl,
    float* __restrict__ out) {
  cg::grid_group gg = cg::this_grid();
  __shared__ unsigned lh[256];
  __shared__ unsigned sPref, sCum;
  __shared__ unsigned long long buf[2][1024];   // 16 KiB, scan phase only
  __shared__ unsigned long long keepW[16];

  int t = threadIdx.x;
  int g = blockIdx.x * THR + t;
  float W = scalar_dim(wp), H = scalar_dim(hp);

  unsigned u[SMAX];

  // ---- P0: decode + level-0 histogram ----
  lh[t] = 0u;
  if (t == 0) { sPref = 0u; sCum = 0u; }
  __syncthreads();
  #pragma unroll
  for (int s = 0; s < SMAX; ++s) {
    int a = g + s * STRIDE;
    u[s] = 0u;
    if (a < A) {
      float m; int mi;
      if (C == 80) {
        const float4* row = (const float4*)(cls + (size_t)a * 80);
        float4 v[20];
        #pragma unroll
        for (int j = 0; j < 20; ++j) v[j] = row[j];   // 20 loads in flight
        float mx[20];
        #pragma unroll
        for (int j = 0; j < 20; ++j)
          mx[j] = fmaxf(fmaxf(v[j].x, v[j].y), fmaxf(v[j].z, v[j].w));
        m = mx[0];
        #pragma unroll
        for (int j = 1; j < 20; ++j) m = fmaxf(m, mx[j]);
        mi = 0x7fffffff;
        #pragma unroll
        for (int j = 0; j < 20; ++j) {
          mi = min(mi, (v[j].x == m) ? 4 * j + 0 : 0x7fffffff);
          mi = min(mi, (v[j].y == m) ? 4 * j + 1 : 0x7fffffff);
          mi = min(mi, (v[j].z == m) ? 4 * j + 2 : 0x7fffffff);
          mi = min(mi, (v[j].w == m) ? 4 * j + 3 : 0x7fffffff);
        }
      } else {                                  // generic fallback
        const float* row = cls + (size_t)a * C;
        m = -3.4e38f; mi = 0;
        for (int j = 0; j < C; ++j) { float v = row[j]; if (v > m) { m = v; mi = j; } }
      }
      float4 an = ((const float4*)anc)[a];
      float4 rg = ((const float4*)reg)[a];
      float wa = an.z - an.x, ha = an.w - an.y;
      float cxa = an.x + 0.5f * wa, cya = an.y + 0.5f * ha;
      float pcx = cxa + rg.x * 0.1f * wa;
      float pcy = cya + rg.y * 0.1f * ha;
      float pw = expf(rg.z * 0.2f) * wa;
      float ph = expf(rg.w * 0.2f) * ha;
      float x1 = fmaxf(pcx - 0.5f * pw, 0.f);
      float y1 = fmaxf(pcy - 0.5f * ph, 0.f);
      float x2 = fminf(pcx + 0.5f * pw, W);
      float y2 = fminf(pcy + 0.5f * ph, H);
      boxes[a] = make_float4(x1, y1, x2, y2);
      ci[a] = mi;
      float msk = (m > PST) ? m : -1.0f;
      u[s] = mapU(msk);
      atomicAdd(&lh[u[s] >> 24], 1u);
    }
  }
  __syncthreads();
  if (lh[t]) atomicAdd(&hist[t], lh[t]);
  gg.sync();

  // ---- P1..P3: radix refinement levels ----
  for (int lev = 1; lev <= 3; ++lev) {
    int shPrev = 32 - 8 * lev;                  // 24, 16, 8
    if (t < 64) select_lds(hist + (lev - 1) * 256, shPrev, &sPref, &sCum);
    __syncthreads();
    unsigned pref = sPref;
    unsigned pm = 0xFFFFFFFFu << shPrev;
    int shCur = shPrev - 8;
    lh[t] = 0u;
    __syncthreads();
    #pragma unroll
    for (int s = 0; s < SMAX; ++s) {
      int a = g + s * STRIDE;
      if (a < A && (u[s] & pm) == pref)
        atomicAdd(&lh[(u[s] >> shCur) & 255u], 1u);
    }
    __syncthreads();
    if (lh[t]) atomicAdd(&hist[lev * 256 + t], lh[t]);
    gg.sync();
  }

  // ---- P4: final select -> uT; compact candidates ----
  if (t < 64) select_lds(hist + 3 * 256, 0, &sPref, &sCum);
  __syncthreads();
  unsigned uT = sPref;
  #pragma unroll
  for (int s = 0; s < SMAX; ++s) {
    int a = g + s * STRIDE;
    if (a < A) {
      unsigned uu = u[s];
      if (uu > uT) {
        unsigned p = atomicAdd(&ctrl[C_CNTA], 1u);   // < 1000 by construction
        if (p < 1000u)
          keyBuf[p] = (((unsigned long long)uu) << 32) | (unsigned)(~a);
      } else if (uu == uT) {
        unsigned p = atomicAdd(&ctrl[C_CNTE], 1u);
        if (p < 3072u)
          keyBuf[1024 + p] = (((unsigned long long)uu) << 32) | (unsigned)(~a);
      }
    }
  }
  gg.sync();

  // ---- P5: rank + gather (one wave per key) ----
  {
    unsigned nTop = ctrl[C_CNTA];
    unsigned nTie = ctrl[C_CNTE]; if (nTie > 3072u) nTie = 3072u;
    int wid = t >> 6, lane = t & 63;
    for (int sidx = blockIdx.x * 4 + wid; sidx < 2048; sidx += GRID * 4) {
      if (sidx < 1024) {                         // top region: rank among tops
        unsigned long long k0 = keyBuf[sidx];
        if (k0 != 0ull) {
          unsigned cnt = 0;
          for (int e = lane; e < 1024; e += 64)
            cnt += (keyBuf[e] > k0) ? 1u : 0u;
          #pragma unroll
          for (int d = 32; d; d >>= 1) cnt += __shfl_down(cnt, d);
          if (lane == 0 && cnt < (unsigned)K_TOP) {
            unsigned idx = ~(unsigned)k0;
            if (idx < (unsigned)A) {
              candS[cnt] = unmapU((unsigned)(k0 >> 32));
              candC[cnt] = ci[idx];
              candB[cnt] = boxes[idx];
            }
          }
        }
      } else {                                   // tie region: rank = nTop + local
        int eIdx = sidx - 1024;
        if (eIdx < (int)nTie) {
          unsigned long long k0 = keyBuf[1024 + eIdx];
          unsigned cnt = 0;
          for (int e = lane; e < (int)nTie; e += 64)
            cnt += (keyBuf[1024 + e] > k0) ? 1u : 0u;
          #pragma unroll
          for (int d = 32; d; d >>= 1) cnt += __shfl_down(cnt, d);
          if (lane == 0) {
            unsigned rank = nTop + cnt;
            if (rank < (unsigned)K_TOP) {
              unsigned idx = ~(unsigned)k0;
              if (idx < (unsigned)A) {
                candS[rank] = unmapU((unsigned)(k0 >> 32));
                candC[rank] = ci[idx];
                candB[rank] = boxes[idx];
              }
            }
          }
        }
      }
    }
  }
  gg.sync();

  // ---- P6: IoU suppression bitmask ----
  for (int g2 = g; g2 < 16 * 1024; g2 += GRID * THR) {
    int i = g2 >> 4, w = g2 & 15;
    unsigned long long bits = 0ull;
    if (i < K_TOP) {
      float4 bi = candB[i];
      float areai = (bi.z - bi.x + 1.f) * (bi.w - bi.y + 1.f);
      int j0 = w << 6;
      #pragma unroll 4
      for (int b = 0; b < 64; ++b) {
        int j = j0 + b;
        if (j > i && j < K_TOP) {
          float4 bj = candB[j];
          float xx1 = fmaxf(bi.x, bj.x);
          float yy1 = fmaxf(bi.y, bj.y);
          float xx2 = fminf(bi.z, bj.z);
          float yy2 = fminf(bi.w, bj.w);
          float iw = fmaxf(xx2 - xx1 + 1.f, 0.f);
          float ih = fmaxf(yy2 - yy1 + 1.f, 0.f);
          float inter = iw * ih;
          float areaj = (bj.z - bj.x + 1.f) * (bj.w - bj.y + 1.f);
          float iou = inter / (areai + areaj - inter);
          if (iou > 0.5f) bits |= (1ull << b);
        }
      }
    }
    maskBuf[g2] = bits;
  }
  gg.sync();

  // ---- P7: serial greedy scan (block 0) + output ----
  if (blockIdx.x != 0) return;

  for (int e = t; e < 1024; e += THR) buf[0][e] = maskBuf[e];
  __syncthreads();

  unsigned long long remv = 0ull;
  int l = t & 63;
  if (t < 64 && l < 16) {
    unsigned long long vb = 0ull;
    for (int b = 0; b < 64; ++b) {
      float s = candS[(l << 6) + b];
      if (s > PST) vb |= (1ull << b);
    }
    remv = ~vb;                                 // invalid start "removed"
  }
  for (int w = 0; w < 16; ++w) {
    if (w + 1 < 16 && t >= 64) {
      for (int e = t - 64; e < 1024; e += THR - 64)
        buf[(w + 1) & 1][e] = maskBuf[(w + 1) * 1024 + e];
    }
    if (t < 64) {
      unsigned long long cw = __shfl(remv, w);
      const unsigned long long* rows = buf[w & 1];
      #pragma unroll
      for (int b = 0; b < 64; ++b) {
        unsigned long long mrow = rows[b * 16 + (l & 15)];
        unsigned long long mvw  = rows[b * 16 + w];
        unsigned long long sel = ((cw >> b) & 1ull) - 1ull;  // removed? 0 : ~0
        remv |= (mrow & sel);
        cw   |= (mvw & sel);
      }
    }
    __syncthreads();
  }
  if (t < 64 && l < 16) keepW[l] = ~remv;
  __syncthreads();

  for (int q = t; q < K_TOP; q += THR) {
    bool kp = (keepW[q >> 6] >> (q & 63)) & 1ull;
    float sc = candS[q];
    int cc = candC[q];
    float4 bb = candB[q];
    out[q] = kp ? sc : 0.f;
    out[K_TOP + q] = kp ? (float)cc : -1.f;
    float4 ob = kp ? bb : make_float4(0.f, 0.f, 0.f, 0.f);
    *(float4*)(out + 2 * K_TOP + 4 * q) = ob;
  }
}

extern "C" void kernel_launch(void* const* d_in, const int* in_sizes, int n_in,
                              void* d_out, int out_size, void* d_ws, size_t ws_size,
                              hipStream_t stream) {
  const float* cls = (const float*)d_in[0];
  const float* reg = (const float*)d_in[1];
  const float* anc = (const float*)d_in[2];
  const int* hp = (const int*)d_in[3];
  const int* wp = (const int*)d_in[4];
  int A = in_sizes[2] / 4;
  int C = in_sizes[0] / A;

  char* ws = (char*)d_ws;
  size_t off = 0;
  auto alloc = [&](size_t bytes) -> void* {
    void* p = ws + off;
    off = (off + bytes + 255) & ~(size_t)255;
    return p;
  };
  float4* boxes = (float4*)alloc((size_t)A * 16);
  int* ci = (int*)alloc((size_t)A * 4);
  unsigned long long* keyBuf = (unsigned long long*)alloc(4096 * 8);
  float* candS = (float*)alloc(1024 * 4);
  int* candC = (int*)alloc(1024 * 4);
  float4* candB = (float4*)alloc(1024 * 16);
  unsigned long long* maskBuf = (unsigned long long*)alloc(16384 * 8);
  unsigned* hist = (unsigned*)alloc(4 * 256 * 4);
  unsigned* ctrl = (unsigned*)alloc(256 * 4);
  (void)ws_size; (void)n_in; (void)out_size;

  float* outp = (float*)d_out;

  hipLaunchKernelGGL(k_init, dim3(1), dim3(1024), 0, stream,
                     hist, ctrl, keyBuf, candS, candC, candB);

  void* args[] = {
    (void*)&cls, (void*)&reg, (void*)&anc, (void*)&hp, (void*)&wp,
    (void*)&A, (void*)&C, (void*)&boxes, (void*)&ci, (void*)&keyBuf,
    (void*)&candS, (void*)&candC, (void*)&candB, (void*)&maskBuf,
    (void*)&hist, (void*)&ctrl, (void*)&outp
  };
  hipLaunchCooperativeKernel((void*)k_main, dim3(GRID), dim3(THR),
                             args, 0, stream);
}

// Round 7
// 278.940 us; speedup vs baseline: 2.0052x; 2.0052x over previous
//
#include <hip/hip_runtime.h>
#include <stdint.h>

#define K_TOP 1000
#define PST 0.05f
#define THR 256
#define NTAIL 64

// ---- ctrl words ----
#define C_DONE0 0
#define C_DONE1 1
#define C_DONE2 2
#define C_BAR   4
#define C_CNTA  6
#define C_CNTE  7
#define C_PREFIX 8
#define C_CUM    9

typedef unsigned long long ull;

__device__ __forceinline__ unsigned mapU(float f) {
  unsigned b = __float_as_uint(f);
  return (b & 0x80000000u) ? ~b : (b | 0x80000000u);
}
__device__ __forceinline__ float unmapU(unsigned u) {
  unsigned b = (u & 0x80000000u) ? (u ^ 0x80000000u) : ~u;
  return __uint_as_float(b);
}
__device__ __forceinline__ float scalar_dim(const int* p) {
  int v = *p;
  if (v > 0 && v < (1 << 20)) return (float)v;
  return __int_as_float(v);
}

// Radix bin selection over NB bins (64 lanes; caller guards t < 64).
// Updates ctrl[C_PREFIX] (selected bits at `shift`) and ctrl[C_CUM] (strictly-above count).
template <int NB>
__device__ void selectN(const unsigned* __restrict__ histL, int shift,
                        unsigned* __restrict__ ctrl) {
  constexpr int PB = NB / 64;
  int t = threadIdx.x;
  unsigned cumIn = ctrl[C_CUM];
  unsigned need = (unsigned)K_TOP - cumIn;   // >= 1
  unsigned h[PB];
  unsigned v = 0;
  #pragma unroll
  for (int b = 0; b < PB; ++b) { h[b] = histL[PB * t + b]; v += h[b]; }
  #pragma unroll
  for (int d = 1; d < 64; d <<= 1) {         // inclusive suffix-sum
    unsigned q = __shfl_down(v, d);
    if (t + d < 64) v += q;
  }
  unsigned sn = __shfl_down(v, 1);
  if (t == 63) sn = 0;
  if (v >= need && sn < need) {              // exactly one lane wins
    unsigned c = sn;
    int bsel = PB * t;
    for (int b = PB - 1; b >= 0; --b) {
      if (c + h[b] >= need) { bsel = PB * t + b; break; }
      c += h[b];
    }
    ctrl[C_PREFIX] = ctrl[C_PREFIX] | (((unsigned)bsel) << shift);
    ctrl[C_CUM] = cumIn + c;
  }
}

// Lightweight grid barrier for a small co-resident grid (NTAIL blocks).
__device__ void gsync(unsigned* bar, unsigned target) {
  __threadfence();                            // release: drain/writeback prior stores
  __syncthreads();
  if (threadIdx.x == 0) {
    __hip_atomic_fetch_add(bar, 1u, __ATOMIC_ACQ_REL, __HIP_MEMORY_SCOPE_AGENT);
    while (__hip_atomic_load(bar, __ATOMIC_ACQUIRE, __HIP_MEMORY_SCOPE_AGENT) < target) {
      __builtin_amdgcn_s_sleep(8);
    }
  }
  __syncthreads();
  __threadfence();                            // acquire: invalidate stale cache lines
}

__global__ void __launch_bounds__(1024) k_init(unsigned* hist, unsigned* ctrl,
                                               ull* keyBuf, float* candS,
                                               int* candC, float4* candB) {
  int t = threadIdx.x;
  for (int e = t; e < 5120; e += 1024) hist[e] = 0u;   // 2048+2048+1024 bins
  if (t < 64) ctrl[t] = 0u;
  for (int e = t; e < 4096; e += 1024) keyBuf[e] = 0ull;
  candS[t] = -1.0f;
  candC[t] = -1;
  candB[t] = make_float4(0.f, 0.f, 0.f, 0.f);
}

// Decode + level-0 (top-11-bit) histogram. pairMode: 2 threads per 80-class row.
__global__ void __launch_bounds__(THR) k_decode(
    const float* __restrict__ cls, const float* __restrict__ reg,
    const float* __restrict__ anc, const int* __restrict__ hp,
    const int* __restrict__ wp, int A, int C, int pairMode,
    float4* __restrict__ boxes, unsigned* __restrict__ su,
    int* __restrict__ ci, unsigned* hist0, unsigned* ctrl, int nb) {
  __shared__ unsigned lh[2048];
  int t = threadIdx.x;
  for (int b = t; b < 2048; b += THR) lh[b] = 0u;
  __syncthreads();
  float W = scalar_dim(wp), H = scalar_dim(hp);

  if (pairMode) {
    int g = blockIdx.x * THR + t;
    if (g < 2 * A) {
      int a = g >> 1, hh = g & 1;
      const float4* rp = (const float4*)(cls + (size_t)a * 80 + hh * 40);
      float4 v[10];
      #pragma unroll
      for (int j = 0; j < 10; ++j) v[j] = rp[j];       // 10 loads in flight
      float mx[10];
      #pragma unroll
      for (int j = 0; j < 10; ++j)
        mx[j] = fmaxf(fmaxf(v[j].x, v[j].y), fmaxf(v[j].z, v[j].w));
      float m = mx[0];
      #pragma unroll
      for (int j = 1; j < 10; ++j) m = fmaxf(m, mx[j]);
      int mi = 0x7fffffff;
      #pragma unroll
      for (int j = 0; j < 10; ++j) {
        mi = min(mi, (v[j].x == m) ? 4 * j + 0 : 0x7fffffff);
        mi = min(mi, (v[j].y == m) ? 4 * j + 1 : 0x7fffffff);
        mi = min(mi, (v[j].z == m) ? 4 * j + 2 : 0x7fffffff);
        mi = min(mi, (v[j].w == m) ? 4 * j + 3 : 0x7fffffff);
      }
      mi += hh * 40;
      float mo = __shfl_xor(m, 1);
      int mio = __shfl_xor(mi, 1);
      if (mo > m) { m = mo; mi = mio; }                // even lane: correct tie-break
      if (hh == 0) {
        float4 an = ((const float4*)anc)[a];
        float4 rg = ((const float4*)reg)[a];
        float wa = an.z - an.x, ha = an.w - an.y;
        float cxa = an.x + 0.5f * wa, cya = an.y + 0.5f * ha;
        float pcx = cxa + rg.x * 0.1f * wa;
        float pcy = cya + rg.y * 0.1f * ha;
        float pw = expf(rg.z * 0.2f) * wa;
        float ph = expf(rg.w * 0.2f) * ha;
        float x1 = fmaxf(pcx - 0.5f * pw, 0.f);
        float y1 = fmaxf(pcy - 0.5f * ph, 0.f);
        float x2 = fminf(pcx + 0.5f * pw, W);
        float y2 = fminf(pcy + 0.5f * ph, H);
        boxes[a] = make_float4(x1, y1, x2, y2);
        ci[a] = mi;
        float msk = (m > PST) ? m : -1.0f;
        unsigned u = mapU(msk);
        su[a] = u;
        atomicAdd(&lh[u >> 21], 1u);
      }
    }
  } else {
    int a = blockIdx.x * THR + t;
    if (a < A) {
      const float* row = cls + (size_t)a * C;
      float m = -3.4e38f; int mi = 0;
      for (int j = 0; j < C; ++j) { float v = row[j]; if (v > m) { m = v; mi = j; } }
      float4 an = ((const float4*)anc)[a];
      float4 rg = ((const float4*)reg)[a];
      float wa = an.z - an.x, ha = an.w - an.y;
      float cxa = an.x + 0.5f * wa, cya = an.y + 0.5f * ha;
      float pcx = cxa + rg.x * 0.1f * wa;
      float pcy = cya + rg.y * 0.1f * ha;
      float pw = expf(rg.z * 0.2f) * wa;
      float ph = expf(rg.w * 0.2f) * ha;
      float x1 = fmaxf(pcx - 0.5f * pw, 0.f);
      float y1 = fmaxf(pcy - 0.5f * ph, 0.f);
      float x2 = fminf(pcx + 0.5f * pw, W);
      float y2 = fminf(pcy + 0.5f * ph, H);
      boxes[a] = make_float4(x1, y1, x2, y2);
      ci[a] = mi;
      float msk = (m > PST) ? m : -1.0f;
      unsigned u = mapU(msk);
      su[a] = u;
      atomicAdd(&lh[u >> 21], 1u);
    }
  }
  __syncthreads();
  for (int b = t; b < 2048; b += THR)
    if (lh[b]) atomicAdd(&hist0[b], lh[b]);
  __shared__ int last;
  __syncthreads();
  if (t == 0) {
    unsigned old = __hip_atomic_fetch_add(&ctrl[C_DONE0], 1u,
                                          __ATOMIC_ACQ_REL, __HIP_MEMORY_SCOPE_AGENT);
    last = (old == (unsigned)(nb - 1));
  }
  __syncthreads();
  if (last && t < 64) selectN<2048>(hist0, 21, ctrl);
}

// Radix refinement pass: histogram next SHIFT-field bits among prefix-matching elems.
template <int NB, int SHIFT>
__global__ void __launch_bounds__(THR) k_hist(
    const unsigned* __restrict__ su, int A, unsigned cmpMask,
    unsigned* hist, unsigned* ctrl, int doneIdx, int nb) {
  __shared__ unsigned lh[NB];
  int t = threadIdx.x;
  for (int b = t; b < NB; b += THR) lh[b] = 0u;
  __syncthreads();
  unsigned pref = ctrl[C_PREFIX];
  for (int a = blockIdx.x * THR + t; a < A; a += gridDim.x * THR) {
    unsigned u = su[a];
    if ((u & cmpMask) == pref) atomicAdd(&lh[(u >> SHIFT) & (NB - 1)], 1u);
  }
  __syncthreads();
  for (int b = t; b < NB; b += THR)
    if (lh[b]) atomicAdd(&hist[b], lh[b]);
  __shared__ int last;
  __syncthreads();
  if (t == 0) {
    unsigned old = __hip_atomic_fetch_add(&ctrl[doneIdx], 1u,
                                          __ATOMIC_ACQ_REL, __HIP_MEMORY_SCOPE_AGENT);
    last = (old == (unsigned)(nb - 1));
  }
  __syncthreads();
  if (last && t < 64) selectN<NB>(hist, SHIFT, ctrl);
}

// Tail: compact -> rank -> mask -> scan, chained with a 64-block spin barrier.
__global__ void __launch_bounds__(THR) k_tail(
    const unsigned* __restrict__ su, int A,
    const float4* __restrict__ boxes, const int* __restrict__ ci,
    ull* __restrict__ keyBuf, float* __restrict__ candS,
    int* __restrict__ candC, float4* __restrict__ candB,
    ull* __restrict__ maskBuf, unsigned* ctrl, float* __restrict__ out) {
  __shared__ ull shmem[2048];                  // 16 KiB, reused per phase
  __shared__ ull keepW[16];
  int t = threadIdx.x;
  unsigned uT = ctrl[C_PREFIX];                // exact u of the K-th largest

  // ---- A: compact ----
  for (int a = blockIdx.x * THR + t; a < A; a += NTAIL * THR) {
    unsigned u = su[a];
    if (u > uT) {
      unsigned p = atomicAdd(&ctrl[C_CNTA], 1u);   // < 1000 by construction
      if (p < 1000u) keyBuf[p] = (((ull)u) << 32) | (unsigned)(~a);
    } else if (u == uT) {
      unsigned p = atomicAdd(&ctrl[C_CNTE], 1u);
      if (p < 3072u) keyBuf[1024 + p] = (((ull)u) << 32) | (unsigned)(~a);
    }
  }
  gsync(&ctrl[C_BAR], NTAIL);

  // ---- B: rank (wave per key, tops staged in LDS) ----
  unsigned nTop = ctrl[C_CNTA];
  unsigned nTie = ctrl[C_CNTE]; if (nTie > 3072u) nTie = 3072u;
  for (int e = t; e < 1024; e += THR) shmem[e] = keyBuf[e];
  __syncthreads();
  int wid = t >> 6, lane = t & 63;
  int gw = blockIdx.x * 4 + wid;               // 0..255
  #pragma unroll
  for (int s2 = 0; s2 < 4; ++s2) {
    int sidx = gw * 4 + s2;                    // 0..1023
    ull k0 = shmem[sidx];
    if (k0 != 0ull) {
      unsigned cnt = 0;
      for (int e = lane; e < 1024; e += 64) cnt += (shmem[e] > k0) ? 1u : 0u;
      #pragma unroll
      for (int d = 32; d; d >>= 1) cnt += __shfl_down(cnt, d);
      if (lane == 0 && cnt < (unsigned)K_TOP) {
        unsigned idx = ~(unsigned)k0;
        candS[cnt] = unmapU((unsigned)(k0 >> 32));
        candC[cnt] = ci[idx];
        candB[cnt] = boxes[idx];
      }
    }
  }
  for (int tix = gw; tix < (int)nTie; tix += NTAIL * 4) {
    ull k0 = keyBuf[1024 + tix];
    unsigned cnt = 0;
    for (int e = lane; e < (int)nTie; e += 64) cnt += (keyBuf[1024 + e] > k0) ? 1u : 0u;
    #pragma unroll
    for (int d = 32; d; d >>= 1) cnt += __shfl_down(cnt, d);
    if (lane == 0) {
      unsigned rank = nTop + cnt;
      if (rank < (unsigned)K_TOP) {
        unsigned idx = ~(unsigned)k0;
        candS[rank] = unmapU((unsigned)(k0 >> 32));
        candC[rank] = ci[idx];
        candB[rank] = boxes[idx];
      }
    }
  }
  gsync(&ctrl[C_BAR], 2 * NTAIL);

  // ---- C: IoU mask (w uniform per wave -> broadcast LDS reads) ----
  float4* sCand = (float4*)shmem;
  for (int e = t; e < 1024; e += THR) sCand[e] = candB[e];
  __syncthreads();
  {
    int g4 = blockIdx.x * THR + t;             // 0..16383
    int i = g4 & 1023, w = g4 >> 10;
    float4 bi = sCand[i];
    float areai = (bi.z - bi.x + 1.f) * (bi.w - bi.y + 1.f);
    ull bits = 0ull;
    if (i < K_TOP) {
      int j0 = w << 6;
      #pragma unroll 4
      for (int b = 0; b < 64; ++b) {
        int j = j0 + b;
        if (j > i && j < K_TOP) {
          float4 bj = sCand[j];
          float xx1 = fmaxf(bi.x, bj.x);
          float yy1 = fmaxf(bi.y, bj.y);
          float xx2 = fminf(bi.z, bj.z);
          float yy2 = fminf(bi.w, bj.w);
          float iw = fmaxf(xx2 - xx1 + 1.f, 0.f);
          float ih = fmaxf(yy2 - yy1 + 1.f, 0.f);
          float inter = iw * ih;
          float areaj = (bj.z - bj.x + 1.f) * (bj.w - bj.y + 1.f);
          float iou = inter / (areai + areaj - inter);
          if (iou > 0.5f) bits |= (1ull << b);
        }
      }
    }
    maskBuf[i * 16 + w] = bits;
  }
  gsync(&ctrl[C_BAR], 3 * NTAIL);

  // ---- D: serial greedy scan (block 0) + output ----
  if (blockIdx.x != 0) return;
  ull (*buf)[1024] = (ull(*)[1024])shmem;
  __syncthreads();
  for (int e = t; e < 1024; e += THR) buf[0][e] = maskBuf[e];
  __syncthreads();

  unsigned long long remv = 0ull;
  int l = t & 63;
  if (t < 64 && l < 16) {
    ull vb = 0ull;
    for (int b = 0; b < 64; ++b) {
      float s = candS[(l << 6) + b];
      if (s > PST) vb |= (1ull << b);
    }
    remv = ~vb;                                // invalid start "removed"
  }
  for (int w = 0; w < 16; ++w) {
    if (w + 1 < 16 && t >= 64) {
      for (int e = t - 64; e < 1024; e += THR - 64)
        buf[(w + 1) & 1][e] = maskBuf[(w + 1) * 1024 + e];
    }
    if (t < 64) {
      ull cw = __shfl(remv, w);
      const ull* rows = buf[w & 1];
      #pragma unroll
      for (int b = 0; b < 64; ++b) {
        ull mrow = rows[b * 16 + (l & 15)];
        ull mvw  = rows[b * 16 + w];
        ull sel = ((cw >> b) & 1ull) - 1ull;   // removed? 0 : ~0
        remv |= (mrow & sel);
        cw   |= (mvw & sel);
      }
    }
    __syncthreads();
  }
  if (t < 64 && l < 16) keepW[l] = ~remv;
  __syncthreads();

  for (int q = t; q < K_TOP; q += THR) {
    bool kp = (keepW[q >> 6] >> (q & 63)) & 1ull;
    float sc = candS[q];
    int cc = candC[q];
    float4 bb = candB[q];
    out[q] = kp ? sc : 0.f;
    out[K_TOP + q] = kp ? (float)cc : -1.f;
    float4 ob = kp ? bb : make_float4(0.f, 0.f, 0.f, 0.f);
    *(float4*)(out + 2 * K_TOP + 4 * q) = ob;
  }
}

extern "C" void kernel_launch(void* const* d_in, const int* in_sizes, int n_in,
                              void* d_out, int out_size, void* d_ws, size_t ws_size,
                              hipStream_t stream) {
  const float* cls = (const float*)d_in[0];
  const float* reg = (const float*)d_in[1];
  const float* anc = (const float*)d_in[2];
  const int* hp = (const int*)d_in[3];
  const int* wp = (const int*)d_in[4];
  int A = in_sizes[2] / 4;
  int C = in_sizes[0] / A;

  char* ws = (char*)d_ws;
  size_t off = 0;
  auto alloc = [&](size_t bytes) -> void* {
    void* p = ws + off;
    off = (off + bytes + 255) & ~(size_t)255;
    return p;
  };
  float4* boxes = (float4*)alloc((size_t)A * 16);
  unsigned* su = (unsigned*)alloc((size_t)A * 4);
  int* ci = (int*)alloc((size_t)A * 4);
  ull* keyBuf = (ull*)alloc(4096 * 8);
  float* candS = (float*)alloc(1024 * 4);
  int* candC = (int*)alloc(1024 * 4);
  float4* candB = (float4*)alloc(1024 * 16);
  ull* maskBuf = (ull*)alloc(16384 * 8);
  unsigned* hist = (unsigned*)alloc(5120 * 4);   // 2048 + 2048 + 1024
  unsigned* ctrl = (unsigned*)alloc(256 * 4);
  (void)ws_size; (void)n_in; (void)out_size;

  int pairMode = (C == 80) ? 1 : 0;
  int nb1 = pairMode ? (2 * A + THR - 1) / THR : (A + THR - 1) / THR;
  int nbH = 512;

  hipLaunchKernelGGL(k_init, dim3(1), dim3(1024), 0, stream,
                     hist, ctrl, keyBuf, candS, candC, candB);
  hipLaunchKernelGGL(k_decode, dim3(nb1), dim3(THR), 0, stream,
                     cls, reg, anc, hp, wp, A, C, pairMode,
                     boxes, su, ci, hist, ctrl, nb1);
  hipLaunchKernelGGL((k_hist<2048, 10>), dim3(nbH), dim3(THR), 0, stream,
                     su, A, 0xFFE00000u, hist + 2048, ctrl, C_DONE1, nbH);
  hipLaunchKernelGGL((k_hist<1024, 0>), dim3(nbH), dim3(THR), 0, stream,
                     su, A, 0xFFFFFC00u, hist + 4096, ctrl, C_DONE2, nbH);
  hipLaunchKernelGGL(k_tail, dim3(NTAIL), dim3(THR), 0, stream,
                     su, A, boxes, ci, keyBuf, candS, candC, candB,
                     maskBuf, ctrl, (float*)d_out);
}

// Round 9
// 248.754 us; speedup vs baseline: 2.2485x; 1.1213x over previous
//
#include <hip/hip_runtime.h>
#include <stdint.h>

#define K_TOP 1000
#define PST 0.05f
#define THR 256
#define NTAIL 64

// ---- ctrl words ----
#define C_DONE0 0
#define C_BAR   4
#define C_CNTA  6
#define C_CNTE  7
#define C_PREFIX 8
#define C_CUM    9

typedef unsigned long long ull;

__device__ __forceinline__ unsigned mapU(float f) {
  unsigned b = __float_as_uint(f);
  return (b & 0x80000000u) ? ~b : (b | 0x80000000u);
}
__device__ __forceinline__ float unmapU(unsigned u) {
  unsigned b = (u & 0x80000000u) ? (u ^ 0x80000000u) : ~u;
  return __uint_as_float(b);
}
__device__ __forceinline__ float scalar_dim(const int* p) {
  int v = *p;
  if (v > 0 && v < (1 << 20)) return (float)v;
  return __int_as_float(v);
}

// ctrl-state radix select (used by k_decode's last block).
template <int NB>
__device__ void selectN(const unsigned* __restrict__ histL, int shift,
                        unsigned* __restrict__ ctrl) {
  constexpr int PB = NB / 64;
  int t = threadIdx.x;
  unsigned cumIn = ctrl[C_CUM];
  unsigned need = (unsigned)K_TOP - cumIn;   // >= 1
  unsigned h[PB];
  unsigned v = 0;
  #pragma unroll
  for (int b = 0; b < PB; ++b) { h[b] = histL[PB * t + b]; v += h[b]; }
  #pragma unroll
  for (int d = 1; d < 64; d <<= 1) {         // inclusive suffix-sum
    unsigned q = __shfl_down(v, d);
    if (t + d < 64) v += q;
  }
  unsigned sn = __shfl_down(v, 1);
  if (t == 63) sn = 0;
  if (v >= need && sn < need) {              // exactly one lane wins
    unsigned c = sn;
    int bsel = PB * t;
    for (int b = PB - 1; b >= 0; --b) {
      if (c + h[b] >= need) { bsel = PB * t + b; break; }
      c += h[b];
    }
    ctrl[C_PREFIX] = ctrl[C_PREFIX] | (((unsigned)bsel) << shift);
    ctrl[C_CUM] = cumIn + c;
  }
}

// LDS-state radix select (per-block private state; all blocks compute identically).
template <int NB>
__device__ void selectL(const unsigned* __restrict__ histL, int shift,
                        unsigned* sPref, unsigned* sCum) {
  constexpr int PB = NB / 64;
  int t = threadIdx.x;                       // caller guards t < 64
  unsigned cumIn = *sCum;
  unsigned need = (unsigned)K_TOP - cumIn;   // >= 1
  unsigned h[PB];
  unsigned v = 0;
  #pragma unroll
  for (int b = 0; b < PB; ++b) { h[b] = histL[PB * t + b]; v += h[b]; }
  #pragma unroll
  for (int d = 1; d < 64; d <<= 1) {
    unsigned q = __shfl_down(v, d);
    if (t + d < 64) v += q;
  }
  unsigned sn = __shfl_down(v, 1);
  if (t == 63) sn = 0;
  if (v >= need && sn < need) {
    unsigned c = sn;
    int bsel = PB * t;
    for (int b = PB - 1; b >= 0; --b) {
      if (c + h[b] >= need) { bsel = PB * t + b; break; }
      c += h[b];
    }
    *sPref = *sPref | (((unsigned)bsel) << shift);
    *sCum = cumIn + c;
  }
}

// Lightweight grid barrier. __syncthreads drains block stores to L2 (write-through
// L1 + vmcnt(0) at barrier); the agent-scope ACQ_REL RMW carries wbl2/inv. No
// per-thread fences (R7: those cost ~100 us in serialized L2 maintenance).
__device__ __forceinline__ void gsync(unsigned* bar, unsigned target) {
  __syncthreads();
  if (threadIdx.x == 0) {
    __hip_atomic_fetch_add(bar, 1u, __ATOMIC_ACQ_REL, __HIP_MEMORY_SCOPE_AGENT);
    while (__hip_atomic_load(bar, __ATOMIC_RELAXED, __HIP_MEMORY_SCOPE_AGENT) < target)
      __builtin_amdgcn_s_sleep(1);
    (void)__hip_atomic_load(bar, __ATOMIC_ACQUIRE, __HIP_MEMORY_SCOPE_AGENT);
  }
  __syncthreads();
}

__global__ void __launch_bounds__(1024) k_init(unsigned* hist, unsigned* ctrl,
                                               ull* keyBuf, float* candS,
                                               int* candC, float4* candB) {
  int t = threadIdx.x;
  for (int e = t; e < 5120; e += 1024) hist[e] = 0u;   // 2048+2048+1024 bins
  if (t < 64) ctrl[t] = 0u;
  for (int e = t; e < 4096; e += 1024) keyBuf[e] = 0ull;
  candS[t] = -1.0f;
  candC[t] = -1;
  candB[t] = make_float4(0.f, 0.f, 0.f, 0.f);
}

// Decode + level-0 (top-11-bit) histogram. pairMode: 2 threads per 80-class row.
__global__ void __launch_bounds__(THR) k_decode(
    const float* __restrict__ cls, const float* __restrict__ reg,
    const float* __restrict__ anc, const int* __restrict__ hp,
    const int* __restrict__ wp, int A, int C, int pairMode,
    float4* __restrict__ boxes, unsigned* __restrict__ su,
    int* __restrict__ ci, unsigned* hist0, unsigned* ctrl, int nb) {
  __shared__ unsigned lh[2048];
  int t = threadIdx.x;
  for (int b = t; b < 2048; b += THR) lh[b] = 0u;
  __syncthreads();
  float W = scalar_dim(wp), H = scalar_dim(hp);

  if (pairMode) {
    int g = blockIdx.x * THR + t;
    if (g < 2 * A) {
      int a = g >> 1, hh = g & 1;
      const float4* rp = (const float4*)(cls + (size_t)a * 80 + hh * 40);
      float4 v[10];
      #pragma unroll
      for (int j = 0; j < 10; ++j) v[j] = rp[j];       // 10 loads in flight
      float mx[10];
      #pragma unroll
      for (int j = 0; j < 10; ++j)
        mx[j] = fmaxf(fmaxf(v[j].x, v[j].y), fmaxf(v[j].z, v[j].w));
      float m = mx[0];
      #pragma unroll
      for (int j = 1; j < 10; ++j) m = fmaxf(m, mx[j]);
      int mi = 0x7fffffff;
      #pragma unroll
      for (int j = 0; j < 10; ++j) {
        mi = min(mi, (v[j].x == m) ? 4 * j + 0 : 0x7fffffff);
        mi = min(mi, (v[j].y == m) ? 4 * j + 1 : 0x7fffffff);
        mi = min(mi, (v[j].z == m) ? 4 * j + 2 : 0x7fffffff);
        mi = min(mi, (v[j].w == m) ? 4 * j + 3 : 0x7fffffff);
      }
      mi += hh * 40;
      float mo = __shfl_xor(m, 1);
      int mio = __shfl_xor(mi, 1);
      if (mo > m) { m = mo; mi = mio; }                // even lane: correct tie-break
      if (hh == 0) {
        float4 an = ((const float4*)anc)[a];
        float4 rg = ((const float4*)reg)[a];
        float wa = an.z - an.x, ha = an.w - an.y;
        float cxa = an.x + 0.5f * wa, cya = an.y + 0.5f * ha;
        float pcx = cxa + rg.x * 0.1f * wa;
        float pcy = cya + rg.y * 0.1f * ha;
        float pw = expf(rg.z * 0.2f) * wa;
        float ph = expf(rg.w * 0.2f) * ha;
        float x1 = fmaxf(pcx - 0.5f * pw, 0.f);
        float y1 = fmaxf(pcy - 0.5f * ph, 0.f);
        float x2 = fminf(pcx + 0.5f * pw, W);
        float y2 = fminf(pcy + 0.5f * ph, H);
        boxes[a] = make_float4(x1, y1, x2, y2);
        ci[a] = mi;
        float msk = (m > PST) ? m : -1.0f;
        unsigned u = mapU(msk);
        su[a] = u;
        atomicAdd(&lh[u >> 21], 1u);
      }
    }
  } else {
    int a = blockIdx.x * THR + t;
    if (a < A) {
      const float* row = cls + (size_t)a * C;
      float m = -3.4e38f; int mi = 0;
      for (int j = 0; j < C; ++j) { float v = row[j]; if (v > m) { m = v; mi = j; } }
      float4 an = ((const float4*)anc)[a];
      float4 rg = ((const float4*)reg)[a];
      float wa = an.z - an.x, ha = an.w - an.y;
      float cxa = an.x + 0.5f * wa, cya = an.y + 0.5f * ha;
      float pcx = cxa + rg.x * 0.1f * wa;
      float pcy = cya + rg.y * 0.1f * ha;
      float pw = expf(rg.z * 0.2f) * wa;
      float ph = expf(rg.w * 0.2f) * ha;
      float x1 = fmaxf(pcx - 0.5f * pw, 0.f);
      float y1 = fmaxf(pcy - 0.5f * ph, 0.f);
      float x2 = fminf(pcx + 0.5f * pw, W);
      float y2 = fminf(pcy + 0.5f * ph, H);
      boxes[a] = make_float4(x1, y1, x2, y2);
      ci[a] = mi;
      float msk = (m > PST) ? m : -1.0f;
      unsigned u = mapU(msk);
      su[a] = u;
      atomicAdd(&lh[u >> 21], 1u);
    }
  }
  __syncthreads();
  for (int b = t; b < 2048; b += THR)
    if (lh[b]) atomicAdd(&hist0[b], lh[b]);
  __shared__ int last;
  __syncthreads();
  if (t == 0) {
    unsigned old = __hip_atomic_fetch_add(&ctrl[C_DONE0], 1u,
                                          __ATOMIC_ACQ_REL, __HIP_MEMORY_SCOPE_AGENT);
    last = (old == (unsigned)(nb - 1));
  }
  __syncthreads();
  if (last && t < 64) selectN<2048>(hist0, 21, ctrl);
}

// Tail: hist1 -> hist2 -> compact -> rank -> mask -> scan, via cheap spin barriers.
__global__ void __launch_bounds__(THR) k_tail(
    const unsigned* __restrict__ su, int A,
    const float4* __restrict__ boxes, const int* __restrict__ ci,
    ull* __restrict__ keyBuf, float* __restrict__ candS,
    int* __restrict__ candC, float4* __restrict__ candB,
    ull* __restrict__ maskBuf, unsigned* hist, unsigned* ctrl,
    float* __restrict__ out) {
  __shared__ ull shmem[2048];                  // 16 KiB, reused per phase
  __shared__ ull keepW[16];
  __shared__ unsigned lh[2048];
  __shared__ unsigned sPref, sCum;
  int t = threadIdx.x;
  int g0 = blockIdx.x * THR + t;

  if (t == 0) { sPref = ctrl[C_PREFIX]; sCum = ctrl[C_CUM]; }  // level-0 result

  // ---- hist level 1 (bits 10..20 of u) ----
  for (int b = t; b < 2048; b += THR) lh[b] = 0u;
  __syncthreads();
  unsigned pref = sPref;
  for (int a = g0; a < A; a += NTAIL * THR) {
    unsigned u = su[a];
    if ((u & 0xFFE00000u) == pref) atomicAdd(&lh[(u >> 10) & 2047u], 1u);
  }
  __syncthreads();
  for (int b = t; b < 2048; b += THR)
    if (lh[b]) atomicAdd(&hist[2048 + b], lh[b]);
  gsync(&ctrl[C_BAR], NTAIL);
  if (t < 64) selectL<2048>(hist + 2048, 10, &sPref, &sCum);
  __syncthreads();

  // ---- hist level 2 (bits 0..9) ----
  for (int b = t; b < 1024; b += THR) lh[b] = 0u;
  __syncthreads();
  pref = sPref;
  for (int a = g0; a < A; a += NTAIL * THR) {
    unsigned u = su[a];
    if ((u & 0xFFFFFC00u) == pref) atomicAdd(&lh[u & 1023u], 1u);
  }
  __syncthreads();
  for (int b = t; b < 1024; b += THR)
    if (lh[b]) atomicAdd(&hist[4096 + b], lh[b]);
  gsync(&ctrl[C_BAR], 2 * NTAIL);
  if (t < 64) selectL<1024>(hist + 4096, 0, &sPref, &sCum);
  __syncthreads();
  unsigned uT = sPref;                         // exact u of the K-th largest

  // ---- compact ----
  for (int a = g0; a < A; a += NTAIL * THR) {
    unsigned u = su[a];
    if (u > uT) {
      unsigned p = atomicAdd(&ctrl[C_CNTA], 1u);   // < 1000 by construction
      if (p < 1000u) keyBuf[p] = (((ull)u) << 32) | (unsigned)(~a);
    } else if (u == uT) {
      unsigned p = atomicAdd(&ctrl[C_CNTE], 1u);
      if (p < 3072u) keyBuf[1024 + p] = (((ull)u) << 32) | (unsigned)(~a);
    }
  }
  gsync(&ctrl[C_BAR], 3 * NTAIL);

  // ---- rank (wave per key, tops staged in LDS) ----
  unsigned nTop = ctrl[C_CNTA];
  unsigned nTie = ctrl[C_CNTE]; if (nTie > 3072u) nTie = 3072u;
  for (int e = t; e < 1024; e += THR) shmem[e] = keyBuf[e];
  __syncthreads();
  int wid = t >> 6, lane = t & 63;
  int gw = blockIdx.x * 4 + wid;               // 0..255
  #pragma unroll
  for (int s2 = 0; s2 < 4; ++s2) {
    int sidx = gw * 4 + s2;                    // 0..1023
    ull k0 = shmem[sidx];
    if (k0 != 0ull) {
      unsigned cnt = 0;
      for (int e = lane; e < 1024; e += 64) cnt += (shmem[e] > k0) ? 1u : 0u;
      #pragma unroll
      for (int d = 32; d; d >>= 1) cnt += __shfl_down(cnt, d);
      if (lane == 0 && cnt < (unsigned)K_TOP) {
        unsigned idx = ~(unsigned)k0;
        candS[cnt] = unmapU((unsigned)(k0 >> 32));
        candC[cnt] = ci[idx];
        candB[cnt] = boxes[idx];
      }
    }
  }
  for (int tix = gw; tix < (int)nTie; tix += NTAIL * 4) {
    ull k0 = keyBuf[1024 + tix];
    unsigned cnt = 0;
    for (int e = lane; e < (int)nTie; e += 64) cnt += (keyBuf[1024 + e] > k0) ? 1u : 0u;
    #pragma unroll
    for (int d = 32; d; d >>= 1) cnt += __shfl_down(cnt, d);
    if (lane == 0) {
      unsigned rank = nTop + cnt;
      if (rank < (unsigned)K_TOP) {
        unsigned idx = ~(unsigned)k0;
        candS[rank] = unmapU((unsigned)(k0 >> 32));
        candC[rank] = ci[idx];
        candB[rank] = boxes[idx];
      }
    }
  }
  gsync(&ctrl[C_BAR], 4 * NTAIL);

  // ---- IoU mask (w uniform per wave -> broadcast LDS reads) ----
  float4* sCand = (float4*)shmem;
  for (int e = t; e < 1024; e += THR) sCand[e] = candB[e];
  __syncthreads();
  {
    int g4 = blockIdx.x * THR + t;             // 0..16383
    int i = g4 & 1023, w = g4 >> 10;
    float4 bi = sCand[i];
    float areai = (bi.z - bi.x + 1.f) * (bi.w - bi.y + 1.f);
    ull bits = 0ull;
    if (i < K_TOP) {
      int j0 = w << 6;
      #pragma unroll 4
      for (int b = 0; b < 64; ++b) {
        int j = j0 + b;
        if (j > i && j < K_TOP) {
          float4 bj = sCand[j];
          float xx1 = fmaxf(bi.x, bj.x);
          float yy1 = fmaxf(bi.y, bj.y);
          float xx2 = fminf(bi.z, bj.z);
          float yy2 = fminf(bi.w, bj.w);
          float iw = fmaxf(xx2 - xx1 + 1.f, 0.f);
          float ih = fmaxf(yy2 - yy1 + 1.f, 0.f);
          float inter = iw * ih;
          float areaj = (bj.z - bj.x + 1.f) * (bj.w - bj.y + 1.f);
          float iou = inter / (areai + areaj - inter);
          if (iou > 0.5f) bits |= (1ull << b);
        }
      }
    }
    maskBuf[i * 16 + w] = bits;
  }
  gsync(&ctrl[C_BAR], 5 * NTAIL);

  // ---- serial greedy scan (block 0) + output ----
  if (blockIdx.x != 0) return;
  ull (*buf)[1024] = (ull(*)[1024])shmem;
  __syncthreads();
  for (int e = t; e < 1024; e += THR) buf[0][e] = maskBuf[e];
  __syncthreads();

  unsigned long long remv = 0ull;
  int l = t & 63;
  if (t < 64 && l < 16) {
    ull vb = 0ull;
    for (int b = 0; b < 64; ++b) {
      float s = candS[(l << 6) + b];
      if (s > PST) vb |= (1ull << b);
    }
    remv = ~vb;                                // invalid start "removed"
  }
  for (int w = 0; w < 16; ++w) {
    if (w + 1 < 16 && t >= 64) {
      for (int e = t - 64; e < 1024; e += THR - 64)
        buf[(w + 1) & 1][e] = maskBuf[(w + 1) * 1024 + e];
    }
    if (t < 64) {
      ull cw = __shfl(remv, w);
      const ull* rows = buf[w & 1];
      #pragma unroll
      for (int b = 0; b < 64; ++b) {
        ull mrow = rows[b * 16 + (l & 15)];
        ull mvw  = rows[b * 16 + w];
        ull sel = ((cw >> b) & 1ull) - 1ull;   // removed? 0 : ~0
        remv |= (mrow & sel);
        cw   |= (mvw & sel);
      }
    }
    __syncthreads();
  }
  if (t < 64 && l < 16) keepW[l] = ~remv;
  __syncthreads();

  for (int q = t; q < K_TOP; q += THR) {
    bool kp = (keepW[q >> 6] >> (q & 63)) & 1ull;
    float sc = candS[q];
    int cc = candC[q];
    float4 bb = candB[q];
    out[q] = kp ? sc : 0.f;
    out[K_TOP + q] = kp ? (float)cc : -1.f;
    float4 ob = kp ? bb : make_float4(0.f, 0.f, 0.f, 0.f);
    *(float4*)(out + 2 * K_TOP + 4 * q) = ob;
  }
}

extern "C" void kernel_launch(void* const* d_in, const int* in_sizes, int n_in,
                              void* d_out, int out_size, void* d_ws, size_t ws_size,
                              hipStream_t stream) {
  const float* cls = (const float*)d_in[0];
  const float* reg = (const float*)d_in[1];
  const float* anc = (const float*)d_in[2];
  const int* hp = (const int*)d_in[3];
  const int* wp = (const int*)d_in[4];
  int A = in_sizes[2] / 4;
  int C = in_sizes[0] / A;

  char* ws = (char*)d_ws;
  size_t off = 0;
  auto alloc = [&](size_t bytes) -> void* {
    void* p = ws + off;
    off = (off + bytes + 255) & ~(size_t)255;
    return p;
  };
  float4* boxes = (float4*)alloc((size_t)A * 16);
  unsigned* su = (unsigned*)alloc((size_t)A * 4);
  int* ci = (int*)alloc((size_t)A * 4);
  ull* keyBuf = (ull*)alloc(4096 * 8);
  float* candS = (float*)alloc(1024 * 4);
  int* candC = (int*)alloc(1024 * 4);
  float4* candB = (float4*)alloc(1024 * 16);
  ull* maskBuf = (ull*)alloc(16384 * 8);
  unsigned* hist = (unsigned*)alloc(5120 * 4);   // 2048 + 2048 + 1024
  unsigned* ctrl = (unsigned*)alloc(256 * 4);
  (void)ws_size; (void)n_in; (void)out_size;

  int pairMode = (C == 80) ? 1 : 0;
  int nb1 = pairMode ? (2 * A + THR - 1) / THR : (A + THR - 1) / THR;

  hipLaunchKernelGGL(k_init, dim3(1), dim3(1024), 0, stream,
                     hist, ctrl, keyBuf, candS, candC, candB);
  hipLaunchKernelGGL(k_decode, dim3(nb1), dim3(THR), 0, stream,
                     cls, reg, anc, hp, wp, A, C, pairMode,
                     boxes, su, ci, hist, ctrl, nb1);
  hipLaunchKernelGGL(k_tail, dim3(NTAIL), dim3(THR), 0, stream,
                     su, A, boxes, ci, keyBuf, candS, candC, candB,
                     maskBuf, hist, ctrl, (float*)d_out);
}

// Round 11
// 228.392 us; speedup vs baseline: 2.4490x; 1.0892x over previous
//
#include <hip/hip_runtime.h>
#include <stdint.h>

#define K_TOP 1000
#define PST 0.05f
#define THR 256
#define NTAIL 64
#define ROWS 128          // rows staged per decode block
#define PADW 81           // padded row width in floats (gcd(81,32)=1 -> conflict-free)

// ---- ctrl words ----
#define C_DONE0 0
#define C_BAR   4
#define C_CNTA  6
#define C_CNTE  7
#define C_PREFIX 8
#define C_CUM    9

typedef unsigned long long ull;

__device__ __forceinline__ unsigned mapU(float f) {
  unsigned b = __float_as_uint(f);
  return (b & 0x80000000u) ? ~b : (b | 0x80000000u);
}
__device__ __forceinline__ float unmapU(unsigned u) {
  unsigned b = (u & 0x80000000u) ? (u ^ 0x80000000u) : ~u;
  return __uint_as_float(b);
}
__device__ __forceinline__ float scalar_dim(const int* p) {
  int v = *p;
  if (v > 0 && v < (1 << 20)) return (float)v;
  return __int_as_float(v);
}

// ---- LLC (coherent) access helpers: relaxed agent-scope atomics bypass the
// ---- non-coherent per-XCD L2s, so no wbl2/inv cache maintenance is needed.
__device__ __forceinline__ unsigned aldU(const unsigned* p) {
  return __hip_atomic_load(p, __ATOMIC_RELAXED, __HIP_MEMORY_SCOPE_AGENT);
}
__device__ __forceinline__ void astU(unsigned* p, unsigned v) {
  __hip_atomic_store(p, v, __ATOMIC_RELAXED, __HIP_MEMORY_SCOPE_AGENT);
}
__device__ __forceinline__ ull aldL(const ull* p) {
  return __hip_atomic_load(p, __ATOMIC_RELAXED, __HIP_MEMORY_SCOPE_AGENT);
}
__device__ __forceinline__ void astL(ull* p, ull v) {
  __hip_atomic_store(p, v, __ATOMIC_RELAXED, __HIP_MEMORY_SCOPE_AGENT);
}

// Fence-free grid barrier: __syncthreads drains vmcnt (stores are at LLC),
// relaxed RMW + relaxed poll (both at LLC). No acquire/release maintenance.
__device__ __forceinline__ void gsync(unsigned* bar, unsigned target) {
  __syncthreads();
  if (threadIdx.x == 0) {
    __hip_atomic_fetch_add(bar, 1u, __ATOMIC_RELAXED, __HIP_MEMORY_SCOPE_AGENT);
    while (__hip_atomic_load(bar, __ATOMIC_RELAXED, __HIP_MEMORY_SCOPE_AGENT) < target)
      __builtin_amdgcn_s_sleep(1);
  }
  __syncthreads();
}

// ctrl-state radix select (used by decode's last block; hist0 lines live only
// at LLC because only atomic RMWs touched them, so plain reads are fresh).
template <int NB>
__device__ void selectN(const unsigned* __restrict__ histL, int shift,
                        unsigned* __restrict__ ctrl) {
  constexpr int PB = NB / 64;
  int t = threadIdx.x;
  unsigned cumIn = ctrl[C_CUM];
  unsigned need = (unsigned)K_TOP - cumIn;   // >= 1
  unsigned h[PB];
  unsigned v = 0;
  #pragma unroll
  for (int b = 0; b < PB; ++b) { h[b] = histL[PB * t + b]; v += h[b]; }
  #pragma unroll
  for (int d = 1; d < 64; d <<= 1) {         // inclusive suffix-sum
    unsigned q = __shfl_down(v, d);
    if (t + d < 64) v += q;
  }
  unsigned sn = __shfl_down(v, 1);
  if (t == 63) sn = 0;
  if (v >= need && sn < need) {              // exactly one lane wins
    unsigned c = sn;
    int bsel = PB * t;
    for (int b = PB - 1; b >= 0; --b) {
      if (c + h[b] >= need) { bsel = PB * t + b; break; }
      c += h[b];
    }
    ctrl[C_PREFIX] = ctrl[C_PREFIX] | (((unsigned)bsel) << shift);
    ctrl[C_CUM] = cumIn + c;
  }
}

// LDS-state radix select; hist read through LLC (aldU).
template <int NB>
__device__ void selectL(const unsigned* __restrict__ histL, int shift,
                        unsigned* sPref, unsigned* sCum) {
  constexpr int PB = NB / 64;
  int t = threadIdx.x;                       // caller guards t < 64
  unsigned cumIn = *sCum;
  unsigned need = (unsigned)K_TOP - cumIn;   // >= 1
  unsigned h[PB];
  unsigned v = 0;
  #pragma unroll
  for (int b = 0; b < PB; ++b) { h[b] = aldU(&histL[PB * t + b]); v += h[b]; }
  #pragma unroll
  for (int d = 1; d < 64; d <<= 1) {
    unsigned q = __shfl_down(v, d);
    if (t + d < 64) v += q;
  }
  unsigned sn = __shfl_down(v, 1);
  if (t == 63) sn = 0;
  if (v >= need && sn < need) {
    unsigned c = sn;
    int bsel = PB * t;
    for (int b = PB - 1; b >= 0; --b) {
      if (c + h[b] >= need) { bsel = PB * t + b; break; }
      c += h[b];
    }
    *sPref = *sPref | (((unsigned)bsel) << shift);
    *sCum = cumIn + c;
  }
}

__device__ __forceinline__ void decode_box(int a, const float4* anc4,
                                           const float4* reg4, float W, float H,
                                           float4* boxes) {
  float4 an = anc4[a];
  float4 rg = reg4[a];
  float wa = an.z - an.x, ha = an.w - an.y;
  float cxa = an.x + 0.5f * wa, cya = an.y + 0.5f * ha;
  float pcx = cxa + rg.x * 0.1f * wa;
  float pcy = cya + rg.y * 0.1f * ha;
  float pw = expf(rg.z * 0.2f) * wa;
  float ph = expf(rg.w * 0.2f) * ha;
  float x1 = fmaxf(pcx - 0.5f * pw, 0.f);
  float y1 = fmaxf(pcy - 0.5f * ph, 0.f);
  float x2 = fminf(pcx + 0.5f * pw, W);
  float y2 = fminf(pcy + 0.5f * ph, H);
  boxes[a] = make_float4(x1, y1, x2, y2);
}

__global__ void __launch_bounds__(1024) k_init(unsigned* hist, unsigned* ctrl,
                                               ull* keyBuf, float* candS,
                                               int* candC, float4* candB) {
  int t = threadIdx.x;
  for (int e = t; e < 5120; e += 1024) hist[e] = 0u;   // 2048+2048+1024 bins
  if (t < 64) ctrl[t] = 0u;
  for (int e = t; e < 4096; e += 1024) keyBuf[e] = 0ull;
  candS[t] = -1.0f;
  candC[t] = -1;
  candB[t] = make_float4(0.f, 0.f, 0.f, 0.f);
}

// LDS-staged decode (C==80): fully-coalesced wave loads (1 KB/instr) into a
// padded LDS tile, then 128 threads reduce one row each. + level-0 histogram.
__global__ void __launch_bounds__(THR) k_decode_staged(
    const float* __restrict__ cls, const float* __restrict__ reg,
    const float* __restrict__ anc, const int* __restrict__ hp,
    const int* __restrict__ wp, int A,
    float4* __restrict__ boxes, unsigned* __restrict__ su,
    int* __restrict__ ci, unsigned* hist0, unsigned* ctrl, int nb) {
  __shared__ float s[ROWS * PADW];             // 41.5 KiB
  __shared__ unsigned lh[2048];                // 8 KiB
  int t = threadIdx.x;
  int r0 = blockIdx.x * ROWS;
  for (int b = t; b < 2048; b += THR) lh[b] = 0u;

  // stage: 2560 float4, thread k takes f = k + 256*i (wave-contiguous)
  const float4* g4 = (const float4*)cls;
  #pragma unroll
  for (int i = 0; i < 10; ++i) {
    int f = t + THR * i;                       // 0..2559
    int row = f / 20, c4 = f % 20;
    if (r0 + row < A) {
      float4 v = g4[(size_t)r0 * 20 + f];
      int base = row * PADW + c4 * 4;
      s[base + 0] = v.x; s[base + 1] = v.y; s[base + 2] = v.z; s[base + 3] = v.w;
    }
  }
  __syncthreads();

  if (t < ROWS) {
    int a = r0 + t;
    if (a < A) {
      const float* rowp = s + t * PADW;
      float m = rowp[0]; int mi = 0;           // sequential first-max == argmax
      #pragma unroll
      for (int j = 1; j < 80; ++j) {
        float v = rowp[j];
        if (v > m) { m = v; mi = j; }
      }
      float W = scalar_dim(wp), H = scalar_dim(hp);
      decode_box(a, (const float4*)anc, (const float4*)reg, W, H, boxes);
      ci[a] = mi;
      float msk = (m > PST) ? m : -1.0f;
      unsigned u = mapU(msk);
      su[a] = u;
      atomicAdd(&lh[u >> 21], 1u);
    }
  }
  __syncthreads();
  for (int b = t; b < 2048; b += THR)
    if (lh[b]) atomicAdd(&hist0[b], lh[b]);
  __shared__ int last;
  __syncthreads();
  if (t == 0) {
    unsigned old = __hip_atomic_fetch_add(&ctrl[C_DONE0], 1u,
                                          __ATOMIC_ACQ_REL, __HIP_MEMORY_SCOPE_AGENT);
    last = (old == (unsigned)(nb - 1));
  }
  __syncthreads();
  if (last && t < 64) selectN<2048>(hist0, 21, ctrl);
}

// Generic fallback (C != 80): one thread per row.
__global__ void __launch_bounds__(THR) k_decode_generic(
    const float* __restrict__ cls, const float* __restrict__ reg,
    const float* __restrict__ anc, const int* __restrict__ hp,
    const int* __restrict__ wp, int A, int C,
    float4* __restrict__ boxes, unsigned* __restrict__ su,
    int* __restrict__ ci, unsigned* hist0, unsigned* ctrl, int nb) {
  __shared__ unsigned lh[2048];
  int t = threadIdx.x;
  for (int b = t; b < 2048; b += THR) lh[b] = 0u;
  __syncthreads();
  int a = blockIdx.x * THR + t;
  if (a < A) {
    const float* row = cls + (size_t)a * C;
    float m = -3.4e38f; int mi = 0;
    for (int j = 0; j < C; ++j) { float v = row[j]; if (v > m) { m = v; mi = j; } }
    float W = scalar_dim(wp), H = scalar_dim(hp);
    decode_box(a, (const float4*)anc, (const float4*)reg, W, H, boxes);
    ci[a] = mi;
    float msk = (m > PST) ? m : -1.0f;
    unsigned u = mapU(msk);
    su[a] = u;
    atomicAdd(&lh[u >> 21], 1u);
  }
  __syncthreads();
  for (int b = t; b < 2048; b += THR)
    if (lh[b]) atomicAdd(&hist0[b], lh[b]);
  __shared__ int last;
  __syncthreads();
  if (t == 0) {
    unsigned old = __hip_atomic_fetch_add(&ctrl[C_DONE0], 1u,
                                          __ATOMIC_ACQ_REL, __HIP_MEMORY_SCOPE_AGENT);
    last = (old == (unsigned)(nb - 1));
  }
  __syncthreads();
  if (last && t < 64) selectN<2048>(hist0, 21, ctrl);
}

// Tail: hist1 -> hist2 -> compact -> rank -> mask -> scan. All cross-block data
// goes through LLC atomics; barriers are fence-free.
__global__ void __launch_bounds__(THR) k_tail(
    const unsigned* __restrict__ su, int A,
    const float4* __restrict__ boxes, const int* __restrict__ ci,
    ull* __restrict__ keyBuf, float* __restrict__ candS,
    int* __restrict__ candC, float4* __restrict__ candB,
    ull* __restrict__ maskBuf, unsigned* hist, unsigned* ctrl,
    float* __restrict__ out) {
  __shared__ ull shmem[2048];                  // 16 KiB, reused per phase
  __shared__ ull keepW[16];
  __shared__ unsigned lh[2048];
  __shared__ unsigned sPref, sCum;
  int t = threadIdx.x;
  int g0 = blockIdx.x * THR + t;

  if (t == 0) { sPref = ctrl[C_PREFIX]; sCum = ctrl[C_CUM]; }  // level-0 result

  // ---- hist level 1 (bits 10..20 of u) ----
  for (int b = t; b < 2048; b += THR) lh[b] = 0u;
  __syncthreads();
  unsigned pref = sPref;
  for (int a = g0; a < A; a += NTAIL * THR) {
    unsigned u = su[a];
    if ((u & 0xFFE00000u) == pref) atomicAdd(&lh[(u >> 10) & 2047u], 1u);
  }
  __syncthreads();
  for (int b = t; b < 2048; b += THR)
    if (lh[b]) atomicAdd(&hist[2048 + b], lh[b]);
  gsync(&ctrl[C_BAR], NTAIL);
  if (t < 64) selectL<2048>(hist + 2048, 10, &sPref, &sCum);
  __syncthreads();

  // ---- hist level 2 (bits 0..9) ----
  for (int b = t; b < 1024; b += THR) lh[b] = 0u;
  __syncthreads();
  pref = sPref;
  for (int a = g0; a < A; a += NTAIL * THR) {
    unsigned u = su[a];
    if ((u & 0xFFFFFC00u) == pref) atomicAdd(&lh[u & 1023u], 1u);
  }
  __syncthreads();
  for (int b = t; b < 1024; b += THR)
    if (lh[b]) atomicAdd(&hist[4096 + b], lh[b]);
  gsync(&ctrl[C_BAR], 2 * NTAIL);
  if (t < 64) selectL<1024>(hist + 4096, 0, &sPref, &sCum);
  __syncthreads();
  unsigned uT = sPref;                         // exact u of the K-th largest

  // ---- compact (keyBuf via LLC stores) ----
  for (int a = g0; a < A; a += NTAIL * THR) {
    unsigned u = su[a];
    if (u > uT) {
      unsigned p = atomicAdd(&ctrl[C_CNTA], 1u);   // < 1000 by construction
      if (p < 1000u) astL(&keyBuf[p], (((ull)u) << 32) | (unsigned)(~a));
    } else if (u == uT) {
      unsigned p = atomicAdd(&ctrl[C_CNTE], 1u);
      if (p < 3072u) astL(&keyBuf[1024 + p], (((ull)u) << 32) | (unsigned)(~a));
    }
  }
  gsync(&ctrl[C_BAR], 3 * NTAIL);

  // ---- rank (wave per key, tops staged in LDS via LLC loads) ----
  unsigned nTop = aldU(&ctrl[C_CNTA]);
  unsigned nTie = aldU(&ctrl[C_CNTE]); if (nTie > 3072u) nTie = 3072u;
  for (int e = t; e < 1024; e += THR) shmem[e] = aldL(&keyBuf[e]);
  __syncthreads();
  int wid = t >> 6, lane = t & 63;
  int gw = blockIdx.x * 4 + wid;               // 0..255
  #pragma unroll
  for (int s2 = 0; s2 < 4; ++s2) {
    int sidx = gw * 4 + s2;                    // 0..1023
    ull k0 = shmem[sidx];
    if (k0 != 0ull) {
      unsigned cnt = 0;
      for (int e = lane; e < 1024; e += 64) cnt += (shmem[e] > k0) ? 1u : 0u;
      #pragma unroll
      for (int d = 32; d; d >>= 1) cnt += __shfl_down(cnt, d);
      if (lane == 0 && cnt < (unsigned)K_TOP) {
        unsigned idx = ~(unsigned)k0;
        float4 bb = boxes[idx];
        astU((unsigned*)&candS[cnt], __float_as_uint(unmapU((unsigned)(k0 >> 32))));
        astU((unsigned*)&candC[cnt], (unsigned)ci[idx]);
        ull* bp = (ull*)&candB[cnt];
        astL(bp, ((ull)__float_as_uint(bb.y) << 32) | __float_as_uint(bb.x));
        astL(bp + 1, ((ull)__float_as_uint(bb.w) << 32) | __float_as_uint(bb.z));
      }
    }
  }
  for (int tix = gw; tix < (int)nTie; tix += NTAIL * 4) {
    ull k0 = aldL(&keyBuf[1024 + tix]);
    unsigned cnt = 0;
    for (int e = lane; e < (int)nTie; e += 64)
      cnt += (aldL(&keyBuf[1024 + e]) > k0) ? 1u : 0u;
    #pragma unroll
    for (int d = 32; d; d >>= 1) cnt += __shfl_down(cnt, d);
    if (lane == 0) {
      unsigned rank = nTop + cnt;
      if (rank < (unsigned)K_TOP) {
        unsigned idx = ~(unsigned)k0;
        float4 bb = boxes[idx];
        astU((unsigned*)&candS[rank], __float_as_uint(unmapU((unsigned)(k0 >> 32))));
        astU((unsigned*)&candC[rank], (unsigned)ci[idx]);
        ull* bp = (ull*)&candB[rank];
        astL(bp, ((ull)__float_as_uint(bb.y) << 32) | __float_as_uint(bb.x));
        astL(bp + 1, ((ull)__float_as_uint(bb.w) << 32) | __float_as_uint(bb.z));
      }
    }
  }
  gsync(&ctrl[C_BAR], 4 * NTAIL);

  // ---- IoU mask (candB via LLC loads, staged; w uniform per wave) ----
  float4* sCand = (float4*)shmem;
  for (int e = t; e < 1024; e += THR) {
    const ull* bp = (const ull*)&candB[e];
    ull lo = aldL(bp), hi = aldL(bp + 1);
    sCand[e] = make_float4(__uint_as_float((unsigned)lo),
                           __uint_as_float((unsigned)(lo >> 32)),
                           __uint_as_float((unsigned)hi),
                           __uint_as_float((unsigned)(hi >> 32)));
  }
  __syncthreads();
  {
    int g4 = blockIdx.x * THR + t;             // 0..16383
    int i = g4 & 1023, w = g4 >> 10;
    float4 bi = sCand[i];
    float areai = (bi.z - bi.x + 1.f) * (bi.w - bi.y + 1.f);
    ull bits = 0ull;
    if (i < K_TOP) {
      int j0 = w << 6;
      #pragma unroll 4
      for (int b = 0; b < 64; ++b) {
        int j = j0 + b;
        if (j > i && j < K_TOP) {
          float4 bj = sCand[j];
          float xx1 = fmaxf(bi.x, bj.x);
          float yy1 = fmaxf(bi.y, bj.y);
          float xx2 = fminf(bi.z, bj.z);
          float yy2 = fminf(bi.w, bj.w);
          float iw = fmaxf(xx2 - xx1 + 1.f, 0.f);
          float ih = fmaxf(yy2 - yy1 + 1.f, 0.f);
          float inter = iw * ih;
          float areaj = (bj.z - bj.x + 1.f) * (bj.w - bj.y + 1.f);
          float iou = inter / (areai + areaj - inter);
          if (iou > 0.5f) bits |= (1ull << b);
        }
      }
    }
    astL(&maskBuf[i * 16 + w], bits);
  }
  gsync(&ctrl[C_BAR], 5 * NTAIL);

  // ---- serial greedy scan (block 0) + output ----
  if (blockIdx.x != 0) return;
  ull (*buf)[1024] = (ull(*)[1024])shmem;
  __syncthreads();
  for (int e = t; e < 1024; e += THR) buf[0][e] = aldL(&maskBuf[e]);
  __syncthreads();

  unsigned long long remv = 0ull;
  int l = t & 63;
  if (t < 64 && l < 16) {
    ull vb = 0ull;
    for (int b = 0; b < 64; ++b) {
      float s = __uint_as_float(aldU((const unsigned*)&candS[(l << 6) + b]));
      if (s > PST) vb |= (1ull << b);
    }
    remv = ~vb;                                // invalid start "removed"
  }
  for (int w = 0; w < 16; ++w) {
    if (w + 1 < 16 && t >= 64) {
      for (int e = t - 64; e < 1024; e += THR - 64)
        buf[(w + 1) & 1][e] = aldL(&maskBuf[(w + 1) * 1024 + e]);
    }
    if (t < 64) {
      ull cw = __shfl(remv, w);
      const ull* rows = buf[w & 1];
      #pragma unroll
      for (int b = 0; b < 64; ++b) {
        ull mrow = rows[b * 16 + (l & 15)];
        ull mvw  = rows[b * 16 + w];
        ull sel = ((cw >> b) & 1ull) - 1ull;   // removed? 0 : ~0
        remv |= (mrow & sel);
        cw   |= (mvw & sel);
      }
    }
    __syncthreads();
  }
  if (t < 64 && l < 16) keepW[l] = ~remv;
  __syncthreads();

  for (int q = t; q < K_TOP; q += THR) {
    bool kp = (keepW[q >> 6] >> (q & 63)) & 1ull;
    float sc = __uint_as_float(aldU((const unsigned*)&candS[q]));
    int cc = (int)aldU((const unsigned*)&candC[q]);
    const ull* bp = (const ull*)&candB[q];
    ull lo = aldL(bp), hi = aldL(bp + 1);
    out[q] = kp ? sc : 0.f;
    out[K_TOP + q] = kp ? (float)cc : -1.f;
    float4 ob = kp ? make_float4(__uint_as_float((unsigned)lo),
                                 __uint_as_float((unsigned)(lo >> 32)),
                                 __uint_as_float((unsigned)hi),
                                 __uint_as_float((unsigned)(hi >> 32)))
                   : make_float4(0.f, 0.f, 0.f, 0.f);
    *(float4*)(out + 2 * K_TOP + 4 * q) = ob;
  }
}

extern "C" void kernel_launch(void* const* d_in, const int* in_sizes, int n_in,
                              void* d_out, int out_size, void* d_ws, size_t ws_size,
                              hipStream_t stream) {
  const float* cls = (const float*)d_in[0];
  const float* reg = (const float*)d_in[1];
  const float* anc = (const float*)d_in[2];
  const int* hp = (const int*)d_in[3];
  const int* wp = (const int*)d_in[4];
  int A = in_sizes[2] / 4;
  int C = in_sizes[0] / A;

  char* ws = (char*)d_ws;
  size_t off = 0;
  auto alloc = [&](size_t bytes) -> void* {
    void* p = ws + off;
    off = (off + bytes + 255) & ~(size_t)255;
    return p;
  };
  float4* boxes = (float4*)alloc((size_t)A * 16);
  unsigned* su = (unsigned*)alloc((size_t)A * 4);
  int* ci = (int*)alloc((size_t)A * 4);
  ull* keyBuf = (ull*)alloc(4096 * 8);
  float* candS = (float*)alloc(1024 * 4);
  int* candC = (int*)alloc(1024 * 4);
  float4* candB = (float4*)alloc(1024 * 16);
  ull* maskBuf = (ull*)alloc(16384 * 8);
  unsigned* hist = (unsigned*)alloc(5120 * 4);   // 2048 + 2048 + 1024
  unsigned* ctrl = (unsigned*)alloc(256 * 4);
  (void)ws_size; (void)n_in; (void)out_size;

  hipLaunchKernelGGL(k_init, dim3(1), dim3(1024), 0, stream,
                     hist, ctrl, keyBuf, candS, candC, candB);
  if (C == 80) {
    int nb = (A + ROWS - 1) / ROWS;
    hipLaunchKernelGGL(k_decode_staged, dim3(nb), dim3(THR), 0, stream,
                       cls, reg, anc, hp, wp, A,
                       boxes, su, ci, hist, ctrl, nb);
  } else {
    int nb = (A + THR - 1) / THR;
    hipLaunchKernelGGL(k_decode_generic, dim3(nb), dim3(THR), 0, stream,
                       cls, reg, anc, hp, wp, A, C,
                       boxes, su, ci, hist, ctrl, nb);
  }
  hipLaunchKernelGGL(k_tail, dim3(NTAIL), dim3(THR), 0, stream,
                     su, A, boxes, ci, keyBuf, candS, candC, candB,
                     maskBuf, hist, ctrl, (float*)d_out);
}

// Round 12
// 223.525 us; speedup vs baseline: 2.5023x; 1.0218x over previous
//
#include <hip/hip_runtime.h>
#include <stdint.h>

#define K_TOP 1000
#define PST 0.05f
#define THR 256
#define NTAIL 64

// ---- ctrl words ----
#define C_DONE0 0
#define C_BAR   4
#define C_BAR2  5
#define C_CNTA  6
#define C_CNTE  7
#define C_PREFIX 8
#define C_CUM    9

typedef unsigned long long ull;

__device__ __forceinline__ unsigned mapU(float f) {
  unsigned b = __float_as_uint(f);
  return (b & 0x80000000u) ? ~b : (b | 0x80000000u);
}
__device__ __forceinline__ float unmapU(unsigned u) {
  unsigned b = (u & 0x80000000u) ? (u ^ 0x80000000u) : ~u;
  return __uint_as_float(b);
}
__device__ __forceinline__ float scalar_dim(const int* p) {
  int v = *p;
  if (v > 0 && v < (1 << 20)) return (float)v;
  return __int_as_float(v);
}

// LLC (coherent) helpers: relaxed agent-scope atomics bypass non-coherent L2s.
__device__ __forceinline__ unsigned aldU(const unsigned* p) {
  return __hip_atomic_load(p, __ATOMIC_RELAXED, __HIP_MEMORY_SCOPE_AGENT);
}
__device__ __forceinline__ void astU(unsigned* p, unsigned v) {
  __hip_atomic_store(p, v, __ATOMIC_RELAXED, __HIP_MEMORY_SCOPE_AGENT);
}
__device__ __forceinline__ ull aldL(const ull* p) {
  return __hip_atomic_load(p, __ATOMIC_RELAXED, __HIP_MEMORY_SCOPE_AGENT);
}
__device__ __forceinline__ void astL(ull* p, ull v) {
  __hip_atomic_store(p, v, __ATOMIC_RELAXED, __HIP_MEMORY_SCOPE_AGENT);
}

// Fence-free grid barrier (64 co-resident blocks).
__device__ __forceinline__ void gsync(unsigned* bar, unsigned target) {
  __syncthreads();
  if (threadIdx.x == 0) {
    __hip_atomic_fetch_add(bar, 1u, __ATOMIC_RELAXED, __HIP_MEMORY_SCOPE_AGENT);
    while (__hip_atomic_load(bar, __ATOMIC_RELAXED, __HIP_MEMORY_SCOPE_AGENT) < target)
      __builtin_amdgcn_s_sleep(1);
  }
  __syncthreads();
}

// ctrl-state radix select (decode's last block).
template <int NB>
__device__ void selectN(const unsigned* __restrict__ histL, int shift,
                        unsigned* __restrict__ ctrl) {
  constexpr int PB = NB / 64;
  int t = threadIdx.x;
  unsigned cumIn = ctrl[C_CUM];
  unsigned need = (unsigned)K_TOP - cumIn;
  unsigned h[PB];
  unsigned v = 0;
  #pragma unroll
  for (int b = 0; b < PB; ++b) { h[b] = histL[PB * t + b]; v += h[b]; }
  #pragma unroll
  for (int d = 1; d < 64; d <<= 1) {
    unsigned q = __shfl_down(v, d);
    if (t + d < 64) v += q;
  }
  unsigned sn = __shfl_down(v, 1);
  if (t == 63) sn = 0;
  if (v >= need && sn < need) {
    unsigned c = sn;
    int bsel = PB * t;
    for (int b = PB - 1; b >= 0; --b) {
      if (c + h[b] >= need) { bsel = PB * t + b; break; }
      c += h[b];
    }
    ctrl[C_PREFIX] = ctrl[C_PREFIX] | (((unsigned)bsel) << shift);
    ctrl[C_CUM] = cumIn + c;
  }
}

// LDS-state radix select; hist read via LLC.
template <int NB>
__device__ void selectL(const unsigned* __restrict__ histL, int shift,
                        unsigned* sPref, unsigned* sCum) {
  constexpr int PB = NB / 64;
  int t = threadIdx.x;                       // caller guards t < 64
  unsigned cumIn = *sCum;
  unsigned need = (unsigned)K_TOP - cumIn;
  unsigned h[PB];
  unsigned v = 0;
  #pragma unroll
  for (int b = 0; b < PB; ++b) { h[b] = aldU(&histL[PB * t + b]); v += h[b]; }
  #pragma unroll
  for (int d = 1; d < 64; d <<= 1) {
    unsigned q = __shfl_down(v, d);
    if (t + d < 64) v += q;
  }
  unsigned sn = __shfl_down(v, 1);
  if (t == 63) sn = 0;
  if (v >= need && sn < need) {
    unsigned c = sn;
    int bsel = PB * t;
    for (int b = PB - 1; b >= 0; --b) {
      if (c + h[b] >= need) { bsel = PB * t + b; break; }
      c += h[b];
    }
    *sPref = *sPref | (((unsigned)bsel) << shift);
    *sCum = cumIn + c;
  }
}

__global__ void __launch_bounds__(1024) k_init(unsigned* hist, unsigned* ctrl,
                                               ull* keyBuf, float* candS,
                                               int* candC, float4* candB) {
  int t = threadIdx.x;
  for (int e = t; e < 5120; e += 1024) hist[e] = 0u;   // 2048+2048+1024 bins
  if (t < 64) ctrl[t] = 0u;
  for (int e = t; e < 4096; e += 1024) keyBuf[e] = 0ull;
  candS[t] = -1.0f;
  candC[t] = -1;
  candB[t] = make_float4(0.f, 0.f, 0.f, 0.f);
}

// Decode: R2-exact inner loop (measured 67us @ 863 GB/s) + 2048-bin level-0 hist.
__global__ void __launch_bounds__(THR) k_decode(
    const float* __restrict__ cls, const float* __restrict__ reg,
    const float* __restrict__ anc, const int* __restrict__ hp,
    const int* __restrict__ wp, int A, int C,
    float4* __restrict__ boxes, unsigned* __restrict__ su,
    int* __restrict__ ci, unsigned* hist0, unsigned* ctrl, int nb) {
  __shared__ unsigned lh[2048];
  int t = threadIdx.x;
  for (int b = t; b < 2048; b += THR) lh[b] = 0u;
  __syncthreads();
  int a = blockIdx.x * THR + t;
  if (a < A) {
    const float* row = cls + (size_t)a * C;
    float m = -3.4e38f; int mi = 0;
    int j = 0;
    for (; j + 4 <= C; j += 4) {
      float4 v = *(const float4*)(row + j);
      if (v.x > m) { m = v.x; mi = j; }
      if (v.y > m) { m = v.y; mi = j + 1; }
      if (v.z > m) { m = v.z; mi = j + 2; }
      if (v.w > m) { m = v.w; mi = j + 3; }
    }
    for (; j < C; ++j) { float v = row[j]; if (v > m) { m = v; mi = j; } }

    float4 an = ((const float4*)anc)[a];
    float4 rg = ((const float4*)reg)[a];
    float wa = an.z - an.x, ha = an.w - an.y;
    float cxa = an.x + 0.5f * wa, cya = an.y + 0.5f * ha;
    float pcx = cxa + rg.x * 0.1f * wa;
    float pcy = cya + rg.y * 0.1f * ha;
    float pw = expf(rg.z * 0.2f) * wa;
    float ph = expf(rg.w * 0.2f) * ha;
    float W = scalar_dim(wp), H = scalar_dim(hp);
    float x1 = fmaxf(pcx - 0.5f * pw, 0.f);
    float y1 = fmaxf(pcy - 0.5f * ph, 0.f);
    float x2 = fminf(pcx + 0.5f * pw, W);
    float y2 = fminf(pcy + 0.5f * ph, H);
    boxes[a] = make_float4(x1, y1, x2, y2);
    ci[a] = mi;
    float msk = (m > PST) ? m : -1.0f;
    unsigned u = mapU(msk);
    su[a] = u;
    atomicAdd(&lh[u >> 21], 1u);
  }
  __syncthreads();
  for (int b = t; b < 2048; b += THR)
    if (lh[b]) atomicAdd(&hist0[b], lh[b]);
  __shared__ int last;
  __syncthreads();
  if (t == 0) {
    unsigned old = __hip_atomic_fetch_add(&ctrl[C_DONE0], 1u,
                                          __ATOMIC_ACQ_REL, __HIP_MEMORY_SCOPE_AGENT);
    last = (old == (unsigned)(nb - 1));
  }
  __syncthreads();
  if (last && t < 64) selectN<2048>(hist0, 21, ctrl);
}

// Selection: hist1 -> sel -> hist2 -> sel -> compact. 64 blocks, 2 barriers.
__global__ void __launch_bounds__(THR) k_sel(
    const unsigned* __restrict__ su, int A, ull* __restrict__ keyBuf,
    unsigned* hist, unsigned* ctrl) {
  __shared__ unsigned lh[2048];
  __shared__ unsigned sPref, sCum;
  int t = threadIdx.x;
  int g0 = blockIdx.x * THR + t;
  if (t == 0) { sPref = ctrl[C_PREFIX]; sCum = ctrl[C_CUM]; }  // level-0 result

  // ---- hist level 1 (bits 10..20) ----
  for (int b = t; b < 2048; b += THR) lh[b] = 0u;
  __syncthreads();
  unsigned pref = sPref;
  for (int a = g0; a < A; a += NTAIL * THR) {
    unsigned u = su[a];
    if ((u & 0xFFE00000u) == pref) atomicAdd(&lh[(u >> 10) & 2047u], 1u);
  }
  __syncthreads();
  {                                           // block-rotated push: spread contention
    int rot = (blockIdx.x * 331) & 2047;
    for (int k = 0; k < 2048; k += THR) {
      int b = (rot + k + t) & 2047;
      if (lh[b]) atomicAdd(&hist[2048 + b], lh[b]);
    }
  }
  gsync(&ctrl[C_BAR], NTAIL);
  if (t < 64) selectL<2048>(hist + 2048, 10, &sPref, &sCum);
  __syncthreads();

  // ---- hist level 2 (bits 0..9) ----
  for (int b = t; b < 1024; b += THR) lh[b] = 0u;
  __syncthreads();
  pref = sPref;
  for (int a = g0; a < A; a += NTAIL * THR) {
    unsigned u = su[a];
    if ((u & 0xFFFFFC00u) == pref) atomicAdd(&lh[u & 1023u], 1u);
  }
  __syncthreads();
  {
    int rot = (blockIdx.x * 331) & 1023;
    for (int k = 0; k < 1024; k += THR) {
      int b = (rot + k + t) & 1023;
      if (lh[b]) atomicAdd(&hist[4096 + b], lh[b]);
    }
  }
  gsync(&ctrl[C_BAR], 2 * NTAIL);
  if (t < 64) selectL<1024>(hist + 4096, 0, &sPref, &sCum);
  __syncthreads();
  unsigned uT = sPref;                         // exact u of the K-th largest

  // ---- compact ----
  for (int a = g0; a < A; a += NTAIL * THR) {
    unsigned u = su[a];
    if (u > uT) {
      unsigned p = atomicAdd(&ctrl[C_CNTA], 1u);   // < 1000 by construction
      if (p < 1000u) astL(&keyBuf[p], (((ull)u) << 32) | (unsigned)(~a));
    } else if (u == uT) {
      unsigned p = atomicAdd(&ctrl[C_CNTE], 1u);
      if (p < 3072u) astL(&keyBuf[1024 + p], (((ull)u) << 32) | (unsigned)(~a));
    }
  }
}

// NMS: rank -> mask -> scan. 64 blocks, 2 barriers.
__global__ void __launch_bounds__(THR) k_nmsall(
    const ull* __restrict__ keyBuf, const float4* __restrict__ boxes,
    const int* __restrict__ ci, int A, float* __restrict__ candS,
    int* __restrict__ candC, float4* __restrict__ candB,
    ull* __restrict__ maskBuf, unsigned* ctrl, float* __restrict__ out) {
  __shared__ ull shmem[2048];                  // 16 KiB, reused per phase
  __shared__ ull keepW[16];
  __shared__ ull vbW[16];
  int t = threadIdx.x;

  // ---- rank (wave per key, tops staged in LDS) ----
  unsigned nTop = aldU(&ctrl[C_CNTA]);
  unsigned nTie = aldU(&ctrl[C_CNTE]); if (nTie > 3072u) nTie = 3072u;
  for (int e = t; e < 1024; e += THR) shmem[e] = aldL(&keyBuf[e]);
  __syncthreads();
  int wid = t >> 6, lane = t & 63;
  int gw = blockIdx.x * 4 + wid;               // 0..255
  #pragma unroll
  for (int s2 = 0; s2 < 4; ++s2) {
    int sidx = gw * 4 + s2;                    // 0..1023
    ull k0 = shmem[sidx];
    if (k0 != 0ull) {
      unsigned cnt = 0;
      for (int e = lane; e < 1024; e += 64) cnt += (shmem[e] > k0) ? 1u : 0u;
      #pragma unroll
      for (int d = 32; d; d >>= 1) cnt += __shfl_down(cnt, d);
      if (lane == 0 && cnt < (unsigned)K_TOP) {
        unsigned idx = ~(unsigned)k0;
        float4 bb = boxes[idx];
        astU((unsigned*)&candS[cnt], __float_as_uint(unmapU((unsigned)(k0 >> 32))));
        astU((unsigned*)&candC[cnt], (unsigned)ci[idx]);
        ull* bp = (ull*)&candB[cnt];
        astL(bp, ((ull)__float_as_uint(bb.y) << 32) | __float_as_uint(bb.x));
        astL(bp + 1, ((ull)__float_as_uint(bb.w) << 32) | __float_as_uint(bb.z));
      }
    }
  }
  for (int tix = gw; tix < (int)nTie; tix += NTAIL * 4) {
    ull k0 = aldL(&keyBuf[1024 + tix]);
    unsigned cnt = 0;
    for (int e = lane; e < (int)nTie; e += 64)
      cnt += (aldL(&keyBuf[1024 + e]) > k0) ? 1u : 0u;
    #pragma unroll
    for (int d = 32; d; d >>= 1) cnt += __shfl_down(cnt, d);
    if (lane == 0) {
      unsigned rank = nTop + cnt;
      if (rank < (unsigned)K_TOP) {
        unsigned idx = ~(unsigned)k0;
        float4 bb = boxes[idx];
        astU((unsigned*)&candS[rank], __float_as_uint(unmapU((unsigned)(k0 >> 32))));
        astU((unsigned*)&candC[rank], (unsigned)ci[idx]);
        ull* bp = (ull*)&candB[rank];
        astL(bp, ((ull)__float_as_uint(bb.y) << 32) | __float_as_uint(bb.x));
        astL(bp + 1, ((ull)__float_as_uint(bb.w) << 32) | __float_as_uint(bb.z));
      }
    }
  }
  gsync(&ctrl[C_BAR2], NTAIL);

  // ---- IoU mask (candB staged to LDS; w uniform per wave) ----
  float4* sCand = (float4*)shmem;
  for (int e = t; e < 1024; e += THR) {
    const ull* bp = (const ull*)&candB[e];
    ull lo = aldL(bp), hi = aldL(bp + 1);
    sCand[e] = make_float4(__uint_as_float((unsigned)lo),
                           __uint_as_float((unsigned)(lo >> 32)),
                           __uint_as_float((unsigned)hi),
                           __uint_as_float((unsigned)(hi >> 32)));
  }
  __syncthreads();
  {
    int g4 = blockIdx.x * THR + t;             // 0..16383
    int i = g4 & 1023, w = g4 >> 10;
    float4 bi = sCand[i];
    float areai = (bi.z - bi.x + 1.f) * (bi.w - bi.y + 1.f);
    ull bits = 0ull;
    if (i < K_TOP) {
      int j0 = w << 6;
      #pragma unroll 4
      for (int b = 0; b < 64; ++b) {
        int j = j0 + b;
        if (j > i && j < K_TOP) {
          float4 bj = sCand[j];
          float xx1 = fmaxf(bi.x, bj.x);
          float yy1 = fmaxf(bi.y, bj.y);
          float xx2 = fminf(bi.z, bj.z);
          float yy2 = fminf(bi.w, bj.w);
          float iw = fmaxf(xx2 - xx1 + 1.f, 0.f);
          float ih = fmaxf(yy2 - yy1 + 1.f, 0.f);
          float inter = iw * ih;
          float areaj = (bj.z - bj.x + 1.f) * (bj.w - bj.y + 1.f);
          float iou = inter / (areai + areaj - inter);
          if (iou > 0.5f) bits |= (1ull << b);
        }
      }
    }
    astL(&maskBuf[i * 16 + w], bits);
  }
  gsync(&ctrl[C_BAR2], 2 * NTAIL);

  // ---- serial greedy scan (block 0) + output ----
  if (blockIdx.x != 0) return;
  ull (*buf)[1024] = (ull(*)[1024])shmem;
  __syncthreads();
  // validity bitmap via coalesced loads + wave ballot
  for (int q = t; q < 1024; q += THR) {
    float s = __uint_as_float(aldU((const unsigned*)&candS[q]));
    ull mball = __ballot(s > PST);             // q 64-aligned per wave
    if ((q & 63) == 0) vbW[q >> 6] = mball;
  }
  for (int e = t; e < 1024; e += THR) buf[0][e] = aldL(&maskBuf[e]);
  __syncthreads();

  ull remv = 0ull;
  int l = t & 63;
  if (t < 64 && l < 16) remv = ~vbW[l];        // invalid start "removed"
  for (int w = 0; w < 16; ++w) {
    if (w + 1 < 16 && t >= 64) {
      for (int e = t - 64; e < 1024; e += THR - 64)
        buf[(w + 1) & 1][e] = aldL(&maskBuf[(w + 1) * 1024 + e]);
    }
    if (t < 64) {
      ull cw = __shfl(remv, w);
      const ull* rows = buf[w & 1];
      #pragma unroll
      for (int b = 0; b < 64; ++b) {
        ull mrow = rows[b * 16 + (l & 15)];
        ull mvw  = rows[b * 16 + w];
        ull sel = ((cw >> b) & 1ull) - 1ull;   // removed? 0 : ~0
        remv |= (mrow & sel);
        cw   |= (mvw & sel);
      }
    }
    __syncthreads();
  }
  if (t < 64 && l < 16) keepW[l] = ~remv;
  __syncthreads();

  for (int q = t; q < K_TOP; q += THR) {
    bool kp = (keepW[q >> 6] >> (q & 63)) & 1ull;
    float sc = __uint_as_float(aldU((const unsigned*)&candS[q]));
    int cc = (int)aldU((const unsigned*)&candC[q]);
    const ull* bp = (const ull*)&candB[q];
    ull lo = aldL(bp), hi = aldL(bp + 1);
    out[q] = kp ? sc : 0.f;
    out[K_TOP + q] = kp ? (float)cc : -1.f;
    float4 ob = kp ? make_float4(__uint_as_float((unsigned)lo),
                                 __uint_as_float((unsigned)(lo >> 32)),
                                 __uint_as_float((unsigned)hi),
                                 __uint_as_float((unsigned)(hi >> 32)))
                   : make_float4(0.f, 0.f, 0.f, 0.f);
    *(float4*)(out + 2 * K_TOP + 4 * q) = ob;
  }
}

extern "C" void kernel_launch(void* const* d_in, const int* in_sizes, int n_in,
                              void* d_out, int out_size, void* d_ws, size_t ws_size,
                              hipStream_t stream) {
  const float* cls = (const float*)d_in[0];
  const float* reg = (const float*)d_in[1];
  const float* anc = (const float*)d_in[2];
  const int* hp = (const int*)d_in[3];
  const int* wp = (const int*)d_in[4];
  int A = in_sizes[2] / 4;
  int C = in_sizes[0] / A;

  char* ws = (char*)d_ws;
  size_t off = 0;
  auto alloc = [&](size_t bytes) -> void* {
    void* p = ws + off;
    off = (off + bytes + 255) & ~(size_t)255;
    return p;
  };
  float4* boxes = (float4*)alloc((size_t)A * 16);
  unsigned* su = (unsigned*)alloc((size_t)A * 4);
  int* ci = (int*)alloc((size_t)A * 4);
  ull* keyBuf = (ull*)alloc(4096 * 8);
  float* candS = (float*)alloc(1024 * 4);
  int* candC = (int*)alloc(1024 * 4);
  float4* candB = (float4*)alloc(1024 * 16);
  ull* maskBuf = (ull*)alloc(16384 * 8);
  unsigned* hist = (unsigned*)alloc(5120 * 4);   // 2048 + 2048 + 1024
  unsigned* ctrl = (unsigned*)alloc(256 * 4);
  (void)ws_size; (void)n_in; (void)out_size;

  int nb = (A + THR - 1) / THR;

  hipLaunchKernelGGL(k_init, dim3(1), dim3(1024), 0, stream,
                     hist, ctrl, keyBuf, candS, candC, candB);
  hipLaunchKernelGGL(k_decode, dim3(nb), dim3(THR), 0, stream,
                     cls, reg, anc, hp, wp, A, C,
                     boxes, su, ci, hist, ctrl, nb);
  hipLaunchKernelGGL(k_sel, dim3(NTAIL), dim3(THR), 0, stream,
                     su, A, keyBuf, hist, ctrl);
  hipLaunchKernelGGL(k_nmsall, dim3(NTAIL), dim3(THR), 0, stream,
                     keyBuf, boxes, ci, A, candS, candC, candB,
                     maskBuf, ctrl, (float*)d_out);
}

// Round 13
// 206.620 us; speedup vs baseline: 2.7070x; 1.0818x over previous
//
#include <hip/hip_runtime.h>
#include <stdint.h>

#define K_TOP 1000
#define PST 0.05f
#define THR 256
#define TTHR 1024
#define NTAIL 64

// ---- ctrl words ----
#define C_DONE0 0
#define C_BAR   4
#define C_CNTA  6
#define C_CNTE  7
#define C_PREFIX 8
#define C_CUM    9

typedef unsigned long long ull;

__device__ __forceinline__ unsigned mapU(float f) {
  unsigned b = __float_as_uint(f);
  return (b & 0x80000000u) ? ~b : (b | 0x80000000u);
}
__device__ __forceinline__ float unmapU(unsigned u) {
  unsigned b = (u & 0x80000000u) ? (u ^ 0x80000000u) : ~u;
  return __uint_as_float(b);
}
__device__ __forceinline__ float scalar_dim(const int* p) {
  int v = *p;
  if (v > 0 && v < (1 << 20)) return (float)v;
  return __int_as_float(v);
}

// LLC (coherent) helpers: relaxed agent-scope atomics bypass non-coherent L2s.
__device__ __forceinline__ unsigned aldU(const unsigned* p) {
  return __hip_atomic_load(p, __ATOMIC_RELAXED, __HIP_MEMORY_SCOPE_AGENT);
}
__device__ __forceinline__ void astU(unsigned* p, unsigned v) {
  __hip_atomic_store(p, v, __ATOMIC_RELAXED, __HIP_MEMORY_SCOPE_AGENT);
}
__device__ __forceinline__ ull aldL(const ull* p) {
  return __hip_atomic_load(p, __ATOMIC_RELAXED, __HIP_MEMORY_SCOPE_AGENT);
}
__device__ __forceinline__ void astL(ull* p, ull v) {
  __hip_atomic_store(p, v, __ATOMIC_RELAXED, __HIP_MEMORY_SCOPE_AGENT);
}

// Fence-free grid barrier (64 co-resident blocks).
__device__ __forceinline__ void gsync(unsigned* bar, unsigned target) {
  __syncthreads();
  if (threadIdx.x == 0) {
    __hip_atomic_fetch_add(bar, 1u, __ATOMIC_RELAXED, __HIP_MEMORY_SCOPE_AGENT);
    while (__hip_atomic_load(bar, __ATOMIC_RELAXED, __HIP_MEMORY_SCOPE_AGENT) < target)
      __builtin_amdgcn_s_sleep(1);
  }
  __syncthreads();
}

// ctrl-state radix select (decode's last block).
template <int NB>
__device__ void selectN(const unsigned* __restrict__ histL, int shift,
                        unsigned* __restrict__ ctrl) {
  constexpr int PB = NB / 64;
  int t = threadIdx.x;
  unsigned cumIn = ctrl[C_CUM];
  unsigned need = (unsigned)K_TOP - cumIn;
  unsigned h[PB];
  unsigned v = 0;
  #pragma unroll
  for (int b = 0; b < PB; ++b) { h[b] = histL[PB * t + b]; v += h[b]; }
  #pragma unroll
  for (int d = 1; d < 64; d <<= 1) {
    unsigned q = __shfl_down(v, d);
    if (t + d < 64) v += q;
  }
  unsigned sn = __shfl_down(v, 1);
  if (t == 63) sn = 0;
  if (v >= need && sn < need) {
    unsigned c = sn;
    int bsel = PB * t;
    for (int b = PB - 1; b >= 0; --b) {
      if (c + h[b] >= need) { bsel = PB * t + b; break; }
      c += h[b];
    }
    ctrl[C_PREFIX] = ctrl[C_PREFIX] | (((unsigned)bsel) << shift);
    ctrl[C_CUM] = cumIn + c;
  }
}

// LDS-state radix select; hist read via LLC.
template <int NB>
__device__ void selectL(const unsigned* __restrict__ histL, int shift,
                        unsigned* sPref, unsigned* sCum) {
  constexpr int PB = NB / 64;
  int t = threadIdx.x;                       // caller guards t < 64
  unsigned cumIn = *sCum;
  unsigned need = (unsigned)K_TOP - cumIn;
  unsigned h[PB];
  unsigned v = 0;
  #pragma unroll
  for (int b = 0; b < PB; ++b) { h[b] = aldU(&histL[PB * t + b]); v += h[b]; }
  #pragma unroll
  for (int d = 1; d < 64; d <<= 1) {
    unsigned q = __shfl_down(v, d);
    if (t + d < 64) v += q;
  }
  unsigned sn = __shfl_down(v, 1);
  if (t == 63) sn = 0;
  if (v >= need && sn < need) {
    unsigned c = sn;
    int bsel = PB * t;
    for (int b = PB - 1; b >= 0; --b) {
      if (c + h[b] >= need) { bsel = PB * t + b; break; }
      c += h[b];
    }
    *sPref = *sPref | (((unsigned)bsel) << shift);
    *sCum = cumIn + c;
  }
}

__global__ void __launch_bounds__(1024) k_init(unsigned* hist, unsigned* ctrl,
                                               ull* keyBuf, float* candS,
                                               int* candC, float4* candB) {
  int t = threadIdx.x;
  for (int e = t; e < 2560; e += 1024) hist[e] = 0u;   // 2048 + 3x128 bins
  if (t < 64) ctrl[t] = 0u;
  for (int e = t; e < 4096; e += 1024) keyBuf[e] = 0ull;
  candS[t] = -1.0f;
  candC[t] = -1;
  candB[t] = make_float4(0.f, 0.f, 0.f, 0.f);
}

// Decode + level-0 (top-11-bit) histogram. C==80 path: 20-deep load pipeline
// forced by sched_barrier(0) between issue and reduce.
__global__ void __launch_bounds__(THR) k_decode(
    const float* __restrict__ cls, const float* __restrict__ reg,
    const float* __restrict__ anc, const int* __restrict__ hp,
    const int* __restrict__ wp, int A, int C,
    float4* __restrict__ boxes, unsigned* __restrict__ su,
    int* __restrict__ ci, unsigned* hist0, unsigned* ctrl, int nb) {
  __shared__ unsigned lh[2048];
  int t = threadIdx.x;
  for (int b = t; b < 2048; b += THR) lh[b] = 0u;
  __syncthreads();
  int a = blockIdx.x * THR + t;
  if (a < A) {
    float m; int mi;
    if (C == 80) {
      const float4* row = (const float4*)(cls + (size_t)a * 80);
      float4 v[20];
      #pragma unroll
      for (int j = 0; j < 20; ++j) v[j] = row[j];
      __builtin_amdgcn_sched_barrier(0);       // all 20 loads issued before any use
      float mx[20];
      #pragma unroll
      for (int j = 0; j < 20; ++j)
        mx[j] = fmaxf(fmaxf(v[j].x, v[j].y), fmaxf(v[j].z, v[j].w));
      m = mx[0];
      #pragma unroll
      for (int j = 1; j < 20; ++j) m = fmaxf(m, mx[j]);
      mi = 0x7fffffff;
      #pragma unroll
      for (int j = 0; j < 20; ++j) {
        mi = min(mi, (v[j].x == m) ? 4 * j + 0 : 0x7fffffff);
        mi = min(mi, (v[j].y == m) ? 4 * j + 1 : 0x7fffffff);
        mi = min(mi, (v[j].z == m) ? 4 * j + 2 : 0x7fffffff);
        mi = min(mi, (v[j].w == m) ? 4 * j + 3 : 0x7fffffff);
      }
    } else {
      const float* row = cls + (size_t)a * C;
      m = -3.4e38f; mi = 0;
      for (int j = 0; j < C; ++j) { float v = row[j]; if (v > m) { m = v; mi = j; } }
    }
    float4 an = ((const float4*)anc)[a];
    float4 rg = ((const float4*)reg)[a];
    float wa = an.z - an.x, ha = an.w - an.y;
    float cxa = an.x + 0.5f * wa, cya = an.y + 0.5f * ha;
    float pcx = cxa + rg.x * 0.1f * wa;
    float pcy = cya + rg.y * 0.1f * ha;
    float pw = expf(rg.z * 0.2f) * wa;
    float ph = expf(rg.w * 0.2f) * ha;
    float W = scalar_dim(wp), H = scalar_dim(hp);
    float x1 = fmaxf(pcx - 0.5f * pw, 0.f);
    float y1 = fmaxf(pcy - 0.5f * ph, 0.f);
    float x2 = fminf(pcx + 0.5f * pw, W);
    float y2 = fminf(pcy + 0.5f * ph, H);
    boxes[a] = make_float4(x1, y1, x2, y2);
    ci[a] = mi;
    float msk = (m > PST) ? m : -1.0f;
    unsigned u = mapU(msk);
    su[a] = u;
    atomicAdd(&lh[u >> 21], 1u);
  }
  __syncthreads();
  for (int b = t; b < 2048; b += THR)
    if (lh[b]) atomicAdd(&hist0[b], lh[b]);
  __shared__ int last;
  __syncthreads();
  if (t == 0) {
    unsigned old = __hip_atomic_fetch_add(&ctrl[C_DONE0], 1u,
                                          __ATOMIC_ACQ_REL, __HIP_MEMORY_SCOPE_AGENT);
    last = (old == (unsigned)(nb - 1));
  }
  __syncthreads();
  if (last && t < 64) selectN<2048>(hist0, 21, ctrl);
}

// Fused tail: 3x 128-bin refinement -> compact -> rank -> mask -> scan.
// 64 blocks x 1024 threads; cross-block data via LLC atomics; fence-free barriers.
__global__ void __launch_bounds__(TTHR) k_tail(
    const unsigned* __restrict__ su, int A,
    const float4* __restrict__ boxes, const int* __restrict__ ci,
    ull* __restrict__ keyBuf, float* __restrict__ candS,
    int* __restrict__ candC, float4* __restrict__ candB,
    ull* __restrict__ maskBuf, unsigned* hist, unsigned* ctrl,
    float* __restrict__ out) {
  __shared__ ull shmem[2048];                  // 16 KiB, reused per phase
  __shared__ ull keepW[16];
  __shared__ ull vbW[16];
  __shared__ unsigned lh[128];
  __shared__ unsigned sPref, sCum;
  int t = threadIdx.x;
  if (t == 0) { sPref = ctrl[C_PREFIX]; sCum = ctrl[C_CUM]; }  // level-0 result

  // ---- refinement levels: bits 14..20 / 7..13 / 0..6 (128 bins each) ----
  #pragma unroll
  for (int lev = 0; lev < 3; ++lev) {
    const int shift = 14 - 7 * lev;            // 14, 7, 0
    const unsigned pm = 0xFFFFFFFFu << (shift + 7);
    unsigned* hl = hist + 2048 + 128 * lev;
    if (t < 128) lh[t] = 0u;
    __syncthreads();
    unsigned pref = sPref;
    for (int a = blockIdx.x * TTHR + t; a < A; a += NTAIL * TTHR) {
      unsigned u = su[a];
      if ((u & pm) == pref) atomicAdd(&lh[(u >> shift) & 127u], 1u);
    }
    __syncthreads();
    if (t < 128 && lh[t]) atomicAdd(&hl[t], lh[t]);
    gsync(&ctrl[C_BAR], (lev + 1) * NTAIL);
    if (t < 64) selectL<128>(hl, shift, &sPref, &sCum);
    __syncthreads();
  }
  unsigned uT = sPref;                         // exact u of the K-th largest

  // ---- compact ----
  for (int a = blockIdx.x * TTHR + t; a < A; a += NTAIL * TTHR) {
    unsigned u = su[a];
    if (u > uT) {
      unsigned p = atomicAdd(&ctrl[C_CNTA], 1u);   // < 1000 by construction
      if (p < 1000u) astL(&keyBuf[p], (((ull)u) << 32) | (unsigned)(~a));
    } else if (u == uT) {
      unsigned p = atomicAdd(&ctrl[C_CNTE], 1u);
      if (p < 3072u) astL(&keyBuf[1024 + p], (((ull)u) << 32) | (unsigned)(~a));
    }
  }
  gsync(&ctrl[C_BAR], 4 * NTAIL);

  // ---- rank (one wave per key; tops staged in LDS) ----
  unsigned nTop = aldU(&ctrl[C_CNTA]);
  unsigned nTie = aldU(&ctrl[C_CNTE]); if (nTie > 3072u) nTie = 3072u;
  if (t < 1024) shmem[t] = aldL(&keyBuf[t]);
  __syncthreads();
  int wid = t >> 6, lane = t & 63;
  int gw = blockIdx.x * 16 + wid;              // 0..1023
  {
    ull k0 = shmem[gw];
    if (k0 != 0ull) {
      unsigned cnt = 0;
      for (int e = lane; e < 1024; e += 64) cnt += (shmem[e] > k0) ? 1u : 0u;
      #pragma unroll
      for (int d = 32; d; d >>= 1) cnt += __shfl_down(cnt, d);
      if (lane == 0 && cnt < (unsigned)K_TOP) {
        unsigned idx = ~(unsigned)k0;
        float4 bb = boxes[idx];
        astU((unsigned*)&candS[cnt], __float_as_uint(unmapU((unsigned)(k0 >> 32))));
        astU((unsigned*)&candC[cnt], (unsigned)ci[idx]);
        ull* bp = (ull*)&candB[cnt];
        astL(bp, ((ull)__float_as_uint(bb.y) << 32) | __float_as_uint(bb.x));
        astL(bp + 1, ((ull)__float_as_uint(bb.w) << 32) | __float_as_uint(bb.z));
      }
    }
  }
  for (int tix = gw; tix < (int)nTie; tix += NTAIL * 16) {
    ull k0 = aldL(&keyBuf[1024 + tix]);
    unsigned cnt = 0;
    for (int e = lane; e < (int)nTie; e += 64)
      cnt += (aldL(&keyBuf[1024 + e]) > k0) ? 1u : 0u;
    #pragma unroll
    for (int d = 32; d; d >>= 1) cnt += __shfl_down(cnt, d);
    if (lane == 0) {
      unsigned rank = nTop + cnt;
      if (rank < (unsigned)K_TOP) {
        unsigned idx = ~(unsigned)k0;
        float4 bb = boxes[idx];
        astU((unsigned*)&candS[rank], __float_as_uint(unmapU((unsigned)(k0 >> 32))));
        astU((unsigned*)&candC[rank], (unsigned)ci[idx]);
        ull* bp = (ull*)&candB[rank];
        astL(bp, ((ull)__float_as_uint(bb.y) << 32) | __float_as_uint(bb.x));
        astL(bp + 1, ((ull)__float_as_uint(bb.w) << 32) | __float_as_uint(bb.z));
      }
    }
  }
  gsync(&ctrl[C_BAR], 5 * NTAIL);

  // ---- IoU mask: blocks 0..15, block b = word-column w=b, thread t = row i ----
  float4* sCand = (float4*)shmem;
  for (int e = t; e < 1024; e += TTHR) {
    const ull* bp = (const ull*)&candB[e];
    ull lo = aldL(bp), hi = aldL(bp + 1);
    sCand[e] = make_float4(__uint_as_float((unsigned)lo),
                           __uint_as_float((unsigned)(lo >> 32)),
                           __uint_as_float((unsigned)hi),
                           __uint_as_float((unsigned)(hi >> 32)));
  }
  __syncthreads();
  if (blockIdx.x < 16) {
    int i = t, w = blockIdx.x;
    float4 bi = sCand[i];
    float areai = (bi.z - bi.x + 1.f) * (bi.w - bi.y + 1.f);
    ull bits = 0ull;
    if (i < K_TOP) {
      int j0 = w << 6;
      #pragma unroll 4
      for (int b = 0; b < 64; ++b) {
        int j = j0 + b;
        if (j > i && j < K_TOP) {
          float4 bj = sCand[j];
          float xx1 = fmaxf(bi.x, bj.x);
          float yy1 = fmaxf(bi.y, bj.y);
          float xx2 = fminf(bi.z, bj.z);
          float yy2 = fminf(bi.w, bj.w);
          float iw = fmaxf(xx2 - xx1 + 1.f, 0.f);
          float ih = fmaxf(yy2 - yy1 + 1.f, 0.f);
          float inter = iw * ih;
          float areaj = (bj.z - bj.x + 1.f) * (bj.w - bj.y + 1.f);
          float iou = inter / (areai + areaj - inter);
          if (iou > 0.5f) bits |= (1ull << b);
        }
      }
    }
    astL(&maskBuf[i * 16 + w], bits);
  }
  gsync(&ctrl[C_BAR], 6 * NTAIL);

  // ---- serial greedy scan (block 0) + output ----
  if (blockIdx.x != 0) return;
  ull (*buf)[1024] = (ull(*)[1024])shmem;
  __syncthreads();
  if (t < 1024) {
    float s = __uint_as_float(aldU((const unsigned*)&candS[t]));
    ull mball = __ballot(s > PST);
    if ((t & 63) == 0) vbW[t >> 6] = mball;
  }
  if (t < 1024) buf[0][t] = aldL(&maskBuf[t]);
  __syncthreads();

  ull remv = 0ull;
  int l = t & 63;
  if (t < 64 && l < 16) remv = ~vbW[l];        // invalid start "removed"
  for (int w = 0; w < 16; ++w) {
    if (w + 1 < 16 && t >= 64) {
      for (int e = t - 64; e < 1024; e += TTHR - 64)
        buf[(w + 1) & 1][e] = aldL(&maskBuf[(w + 1) * 1024 + e]);
    }
    if (t < 64) {
      ull cw = __shfl(remv, w);
      const ull* rows = buf[w & 1];
      #pragma unroll
      for (int b = 0; b < 64; ++b) {
        ull mrow = rows[b * 16 + (l & 15)];
        ull mvw  = rows[b * 16 + w];
        ull sel = ((cw >> b) & 1ull) - 1ull;   // removed? 0 : ~0
        remv |= (mrow & sel);
        cw   |= (mvw & sel);
      }
    }
    __syncthreads();
  }
  if (t < 64 && l < 16) keepW[l] = ~remv;
  __syncthreads();

  for (int q = t; q < K_TOP; q += TTHR) {
    bool kp = (keepW[q >> 6] >> (q & 63)) & 1ull;
    float sc = __uint_as_float(aldU((const unsigned*)&candS[q]));
    int cc = (int)aldU((const unsigned*)&candC[q]);
    const ull* bp = (const ull*)&candB[q];
    ull lo = aldL(bp), hi = aldL(bp + 1);
    out[q] = kp ? sc : 0.f;
    out[K_TOP + q] = kp ? (float)cc : -1.f;
    float4 ob = kp ? make_float4(__uint_as_float((unsigned)lo),
                                 __uint_as_float((unsigned)(lo >> 32)),
                                 __uint_as_float((unsigned)hi),
                                 __uint_as_float((unsigned)(hi >> 32)))
                   : make_float4(0.f, 0.f, 0.f, 0.f);
    *(float4*)(out + 2 * K_TOP + 4 * q) = ob;
  }
}

extern "C" void kernel_launch(void* const* d_in, const int* in_sizes, int n_in,
                              void* d_out, int out_size, void* d_ws, size_t ws_size,
                              hipStream_t stream) {
  const float* cls = (const float*)d_in[0];
  const float* reg = (const float*)d_in[1];
  const float* anc = (const float*)d_in[2];
  const int* hp = (const int*)d_in[3];
  const int* wp = (const int*)d_in[4];
  int A = in_sizes[2] / 4;
  int C = in_sizes[0] / A;

  char* ws = (char*)d_ws;
  size_t off = 0;
  auto alloc = [&](size_t bytes) -> void* {
    void* p = ws + off;
    off = (off + bytes + 255) & ~(size_t)255;
    return p;
  };
  float4* boxes = (float4*)alloc((size_t)A * 16);
  unsigned* su = (unsigned*)alloc((size_t)A * 4);
  int* ci = (int*)alloc((size_t)A * 4);
  ull* keyBuf = (ull*)alloc(4096 * 8);
  float* candS = (float*)alloc(1024 * 4);
  int* candC = (int*)alloc(1024 * 4);
  float4* candB = (float4*)alloc(1024 * 16);
  ull* maskBuf = (ull*)alloc(16384 * 8);
  unsigned* hist = (unsigned*)alloc(2560 * 4);   // 2048 + 3x128
  unsigned* ctrl = (unsigned*)alloc(256 * 4);
  (void)ws_size; (void)n_in; (void)out_size;

  int nb = (A + THR - 1) / THR;

  hipLaunchKernelGGL(k_init, dim3(1), dim3(1024), 0, stream,
                     hist, ctrl, keyBuf, candS, candC, candB);
  hipLaunchKernelGGL(k_decode, dim3(nb), dim3(THR), 0, stream,
                     cls, reg, anc, hp, wp, A, C,
                     boxes, su, ci, hist, ctrl, nb);
  hipLaunchKernelGGL(k_tail, dim3(NTAIL), dim3(TTHR), 0, stream,
                     su, A, boxes, ci, keyBuf, candS, candC, candB,
                     maskBuf, hist, ctrl, (float*)d_out);
}